// Round 11
// baseline (460.395 us; speedup 1.0000x reference)
//
#include <hip/hip_runtime.h>
#include <cstdint>

#define AS1 __attribute__((address_space(1)))
#define AS3 __attribute__((address_space(3)))

typedef __bf16 bf16x8 __attribute__((ext_vector_type(8)));
typedef __bf16 bf16x4 __attribute__((ext_vector_type(4)));
typedef float  f32x4  __attribute__((ext_vector_type(4)));

// Per-batch element strides
#define XB_STRIDE   4194304ul   // 4096*1024 bf16 (also Qb, Vt, input-slice fp32)
#define SC_STRIDE   16777216ul  // 4096*4096 fp32
#define P_STRIDE    33554432ul  // score batch stride in bf16 units
#define OUT_STRIDE  8388608ul   // 2048*4096 fp32

// ---------------------------------------------------------------------------
// ALGEBRA (round 11): scores = (XWq+bq)(XWk+bk)^T / sqrt(K)
//   = X (Wq_s Wk^T) X^T + a_i + b_j + c,  Wq_s = Wq/32.
// a_i, c are constant per softmax row -> cancel exactly. Only b_j = X·(Wk bq)
// survives; added in softmax next to the alibi term. So the K projection is
// eliminated: Q'' = X·Mt (Mt = transpose of Wq_s Wk^T), scores = Q''·X^T.
// ---------------------------------------------------------------------------

// Copy input [B][1024][4096] fp32 into top half of out [B][2048][4096]
__global__ void copy_in_k(const float4* __restrict__ in, float4* __restrict__ out) {
  int i = blockIdx.x * 256 + threadIdx.x;       // 4*1024*4096/4 = 4194304
  int b = i >> 20;
  int r = i & 1048575;
  out[(long)b * 2097152 + r] = in[i];
}

// input slice [1024][4096] fp32 -> xb [4096][1024] bf16 (tiled transpose), batched z
__global__ void transpose_x_k(const float* __restrict__ in, __bf16* __restrict__ out) {
  in  += (size_t)blockIdx.z * XB_STRIDE;
  out += (size_t)blockIdx.z * XB_STRIDE;
  __shared__ float t[32][33];
  int s0 = blockIdx.x * 32, c0 = blockIdx.y * 32;
  int tx = threadIdx.x, ty = threadIdx.y;
#pragma unroll
  for (int i = 0; i < 4; i++)
    t[ty + i * 8][tx] = in[(c0 + ty + i * 8) * 4096 + s0 + tx];
  __syncthreads();
#pragma unroll
  for (int i = 0; i < 4; i++)
    out[(s0 + ty + i * 8) * 1024 + c0 + tx] = (__bf16)t[tx][ty + i * 8];
}

// Wq/Wk fp32 [1024][1024] -> bf16 copies (row-major, Wq scaled 1/32)
__global__ void convert_w_k(const float* __restrict__ Wq, const float* __restrict__ Wk,
                            __bf16* __restrict__ Wq_nb, __bf16* __restrict__ Wk_nb) {
  int row = blockIdx.x, sel = blockIdx.y, t = threadIdx.x;
  const float* src = (sel ? Wk : Wq) + (size_t)row * 1024;
  __bf16* dst = (sel ? Wk_nb : Wq_nb) + (size_t)row * 1024;
  float scale = sel ? 1.0f : 0.03125f;
  float4 v = ((const float4*)src)[t];
  bf16x4 o;
  o[0] = (__bf16)(v.x * scale); o[1] = (__bf16)(v.y * scale);
  o[2] = (__bf16)(v.z * scale); o[3] = (__bf16)(v.w * scale);
  ((bf16x4*)dst)[t] = o;
}

// Wv [1024][1024] fp32 -> Wcat rows [1024,2048) bf16 transposed ([n][c])
__global__ void transpose_wv_k(const float* __restrict__ Wv, __bf16* __restrict__ Wcat) {
  __shared__ float t[32][33];
  int n0 = blockIdx.x * 32, c0 = blockIdx.y * 32;
  int tx = threadIdx.x, ty = threadIdx.y;
#pragma unroll
  for (int i = 0; i < 4; i++)
    t[ty + i * 8][tx] = Wv[(c0 + ty + i * 8) * 1024 + n0 + tx];
  __syncthreads();
#pragma unroll
  for (int i = 0; i < 4; i++)
    Wcat[(size_t)(1024 + n0 + ty + i * 8) * 1024 + c0 + tx] = (__bf16)t[tx][ty + i * 8];
}

// wtld[c] = sum_n Wk[c][n] * bq[n]  (fp32 source, one block per row)
__global__ void wtld_k(const float* __restrict__ Wk, const float* __restrict__ bq,
                       float* __restrict__ wtld) {
  __shared__ float red[4];
  int c = blockIdx.x, tid = threadIdx.x, lane = tid & 63, wid = tid >> 6;
  float4 w = ((const float4*)(Wk + (size_t)c * 1024))[tid];
  float4 b = ((const float4*)bq)[tid];
  float s = w.x * b.x + w.y * b.y + w.z * b.z + w.w * b.w;
#pragma unroll
  for (int o = 32; o; o >>= 1) s += __shfl_xor(s, o, 64);
  if (lane == 0) red[wid] = s;
  __syncthreads();
  if (tid == 0) wtld[c] = red[0] + red[1] + red[2] + red[3];
}

// bvec[z][j] = xb[z][j,:] . wtld  (the b_j softmax column bias)
__global__ void bvec_k(const __bf16* __restrict__ xb, const float* __restrict__ wtld,
                       float* __restrict__ bvec) {
  xb += (size_t)blockIdx.y * XB_STRIDE;
  bvec += (size_t)blockIdx.y * 4096;
  __shared__ float red[4];
  int j = blockIdx.x, tid = threadIdx.x, lane = tid & 63, wid = tid >> 6;
  bf16x4 v = ((const bf16x4*)(xb + (size_t)j * 1024))[tid];
  float4 w = ((const float4*)wtld)[tid];
  float s = (float)v[0] * w.x + (float)v[1] * w.y + (float)v[2] * w.z + (float)v[3] * w.w;
#pragma unroll
  for (int o = 32; o; o >>= 1) s += __shfl_xor(s, o, 64);
  if (lane == 0) red[wid] = s;
  __syncthreads();
  if (tid == 0) bvec[j] = red[0] + red[1] + red[2] + red[3];
}

// ---------------------------------------------------------------------------
// 128x128 depth-2 pipelined core (round-6): used by PV and the Mt precompute.
__device__ __forceinline__ void gemm128_core(const __bf16* __restrict__ A, int lda, int m0,
                                             const __bf16* __restrict__ B, int ldb, int n0,
                                             int nt, __bf16 (*As)[4096], __bf16 (*Bs)[4096],
                                             f32x4 acc[4][4]) {
  const int tid = threadIdx.x;
  const int lane = tid & 63;
  const int wid = tid >> 6;
  const int wr = wid >> 1, wc = wid & 1;
  const int lr = lane & 15;
  const int lk = (lane >> 4) << 3;
  const int srow = tid >> 2;
  const int skq = (tid & 3) << 3;
  const __bf16* ga = A + (long)(m0 + srow) * lda + skq;
  const __bf16* gb = B + (long)(n0 + srow) * ldb + skq;

#define STAGE(t, j) do {                                                                                             \
    int k0_ = (t) * 32;                                                                                              \
    __builtin_amdgcn_global_load_lds((const AS1 void*)(ga + k0_),            (AS3 void*)(As[j] + tid * 8),        16, 0, 0); \
    __builtin_amdgcn_global_load_lds((const AS1 void*)(ga + k0_ + 64 * lda), (AS3 void*)(As[j] + tid * 8 + 2048), 16, 0, 0); \
    __builtin_amdgcn_global_load_lds((const AS1 void*)(gb + k0_),            (AS3 void*)(Bs[j] + tid * 8),        16, 0, 0); \
    __builtin_amdgcn_global_load_lds((const AS1 void*)(gb + k0_ + 64 * ldb), (AS3 void*)(Bs[j] + tid * 8 + 2048), 16, 0, 0); \
  } while (0)

  STAGE(0, 0);
  if (nt > 1) STAGE(1, 1);

  for (int t = 0; t < nt; ++t) {
    const int j = t & 1;
    if (t + 1 < nt) asm volatile("s_waitcnt vmcnt(4)" ::: "memory");
    else            asm volatile("s_waitcnt vmcnt(0)" ::: "memory");
    __builtin_amdgcn_s_barrier();
    __builtin_amdgcn_sched_barrier(0);

    bf16x8 af[4], bfr[4];
#pragma unroll
    for (int m = 0; m < 4; m++)
      af[m] = *(const bf16x8*)(As[j] + (wr * 64 + m * 16 + lr) * 32 + lk);
#pragma unroll
    for (int n = 0; n < 4; n++)
      bfr[n] = *(const bf16x8*)(Bs[j] + (wc * 64 + n * 16 + lr) * 32 + lk);
#pragma unroll
    for (int m = 0; m < 4; m++)
#pragma unroll
      for (int n = 0; n < 4; n++)
        acc[m][n] = __builtin_amdgcn_mfma_f32_16x16x32_bf16(af[m], bfr[n], acc[m][n], 0, 0, 0);

    asm volatile("s_waitcnt lgkmcnt(0)" ::: "memory");
    __builtin_amdgcn_sched_barrier(0);
    __builtin_amdgcn_s_barrier();
    __builtin_amdgcn_sched_barrier(0);
    if (t + 2 < nt) STAGE(t + 2, j);
  }
#undef STAGE
}

// Mt = (Wq_s Wk^T)^T into Wcat rows [0,1024): Mt[c'][c] = sum_n Wk[c'][n] Wq_s[c][n]
__global__ void wqwk_k(const __bf16* __restrict__ Wk_nb, const __bf16* __restrict__ Wq_nb,
                       __bf16* __restrict__ Wcat) {
  __shared__ __bf16 As[2][4096], Bs[2][4096];
  f32x4 acc[4][4] = {};
  int m0 = blockIdx.y * 128, n0 = blockIdx.x * 128;
  gemm128_core(Wk_nb, 1024, m0, Wq_nb, 1024, n0, 32, As, Bs, acc);

  const int lane = threadIdx.x & 63;
  const int wid = threadIdx.x >> 6;
  const int wr = wid >> 1, wc = wid & 1;
  const int lr = lane & 15;
  const int lg = (lane >> 4) * 4;
#pragma unroll
  for (int m = 0; m < 4; m++) {
    int rs = m0 + wr * 64 + m * 16 + lg;
#pragma unroll
    for (int n = 0; n < 4; n++) {
      int col = n0 + wc * 64 + n * 16 + lr;
#pragma unroll
      for (int r = 0; r < 4; r++)
        Wcat[(size_t)(rs + r) * 1024 + col] = (__bf16)acc[m][n][r];
    }
  }
}

// ---------------------------------------------------------------------------
// 256x256 BK=64 streaming GEMM core (round 10; bank-conflict-free swizzle,
// counted vmcnt, 2 barriers/K-tile). Unchanged.
// ---------------------------------------------------------------------------
template<int MH, int NH>
__device__ __forceinline__ void mf_quad(f32x4 (&acc)[8][4], bf16x8 (&aR)[4][2],
                                        bf16x8 (&br)[2][2]) {
#pragma unroll
  for (int q = 0; q < 4; q++)
#pragma unroll
    for (int r = 0; r < 2; r++) {
      acc[MH * 4 + q][NH * 2 + r] = __builtin_amdgcn_mfma_f32_16x16x32_bf16(
          aR[q][0], br[r][0], acc[MH * 4 + q][NH * 2 + r], 0, 0, 0);
      acc[MH * 4 + q][NH * 2 + r] = __builtin_amdgcn_mfma_f32_16x16x32_bf16(
          aR[q][1], br[r][1], acc[MH * 4 + q][NH * 2 + r], 0, 0, 0);
    }
}

__device__ __forceinline__ void gemm256_core(const __bf16* __restrict__ A, int lda, int m0,
                                             const __bf16* __restrict__ B, int ldb, int n0,
                                             __bf16* lds, f32x4 (&acc)[8][4]) {
  const int tid = threadIdx.x;
  const int l = tid & 63;
  const int w = tid >> 6;
  const int wm = w >> 2, wn = w & 3;
  const int lr = l & 15, kg = l >> 4;
  const int lrow = l >> 3;
  const int scol = ((l & 7) ^ lrow) << 3;
  const int xorv = (lr & 7) << 4;
  const int cc0 = (kg << 4) ^ xorv;
  const int cc1 = (64 | (kg << 4)) ^ xorv;
  const int ch = w * 2;
  const char* ldsA = (const char*)lds + wm * 16384;
  const char* ldsB = (const char*)lds + 32768 + (wn >> 1) * 16384;
  const int browb = (wn & 1) * 64;

#define STG8(PTR, LD, BASE0, H, TT, JB, OPOFF) do {                                              \
    const __bf16* sp_ = (PTR) + (size_t)((BASE0) + (H) * 128 + ch * 8 + lrow) * (LD) +           \
                        (TT) * 64 + scol;                                                        \
    __bf16* dp_ = lds + ((JB) * 32768 + (OPOFF) + (H) * 8192 + ch * 512);                        \
    __builtin_amdgcn_global_load_lds((const AS1 void*)sp_,                   (AS3 void*)dp_,         16, 0, 0); \
    __builtin_amdgcn_global_load_lds((const AS1 void*)(sp_ + (size_t)8 * (LD)), (AS3 void*)(dp_ + 512), 16, 0, 0); \
  } while (0)
#define STGA(H, TT, JB) STG8(A, lda, m0, H, TT, JB, 0)
#define STGB(H, TT, JB) STG8(B, ldb, n0, H, TT, JB, 16384)
#define LDAF(dst, MH_, Q_) do {                                                                  \
    const char* p_ = ldsA + jbyte + ((MH_) * 64 + (Q_) * 16 + lr) * 128;                         \
    (dst)[0] = *(const bf16x8*)(p_ + cc0);                                                       \
    (dst)[1] = *(const bf16x8*)(p_ + cc1);                                                       \
  } while (0)
#define LDBF(dst, NH_, R_) do {                                                                  \
    const char* p_ = ldsB + jbyte + (browb + ((NH_) * 2 + (R_)) * 16 + lr) * 128;                \
    (dst)[0] = *(const bf16x8*)(p_ + cc0);                                                       \
    (dst)[1] = *(const bf16x8*)(p_ + cc1);                                                       \
  } while (0)

  STGA(0, 0, 0); STGA(1, 0, 0); STGB(0, 0, 0); STGB(1, 0, 0);
  STGB(0, 1, 1); STGA(0, 1, 1);
  asm volatile("s_waitcnt vmcnt(4)" ::: "memory");
  __builtin_amdgcn_sched_barrier(0);
  __builtin_amdgcn_s_barrier();

  bf16x8 aR[4][2], b0r[2][2], b1r[2][2];
  for (int t = 0; t < 16; ++t) {
    const int j = t & 1, jo = j ^ 1;
    const int jbyte = j * 65536;

#pragma unroll
    for (int q = 0; q < 4; q++) LDAF(aR[q], 0, q);
#pragma unroll
    for (int r = 0; r < 2; r++) LDBF(b0r[r], 0, r);
#pragma unroll
    for (int r = 0; r < 2; r++) LDBF(b1r[r], 1, r);
    if (t < 15) { STGA(1, t + 1, jo); STGB(1, t + 1, jo); }

    __builtin_amdgcn_s_setprio(1);
    mf_quad<0, 0>(acc, aR, b0r);
    mf_quad<0, 1>(acc, aR, b1r);
    __builtin_amdgcn_s_setprio(0);

#pragma unroll
    for (int q = 0; q < 4; q++) LDAF(aR[q], 1, q);
    __builtin_amdgcn_s_setprio(1);
    mf_quad<1, 1>(acc, aR, b1r);
    __builtin_amdgcn_s_setprio(0);

    asm volatile("s_waitcnt lgkmcnt(0)" ::: "memory");
    __builtin_amdgcn_sched_barrier(0);
    __builtin_amdgcn_s_barrier();
    if (t < 14) { STGB(0, t + 2, j); STGA(0, t + 2, j); }

    __builtin_amdgcn_s_setprio(1);
    mf_quad<1, 0>(acc, aR, b0r);
    __builtin_amdgcn_s_setprio(0);

    if (t < 14) asm volatile("s_waitcnt vmcnt(4)" ::: "memory");
    else        asm volatile("s_waitcnt vmcnt(0)" ::: "memory");
    __builtin_amdgcn_sched_barrier(0);
    __builtin_amdgcn_s_barrier();
  }
#undef STG8
#undef STGA
#undef STGB
#undef LDAF
#undef LDBF
}

// ---------------------------------------------------------------------------
// Q''/V projection (batched z): [4096 x 2048] = xb @ Wcat^T.
// cols 0-1023 -> Q'' (no bias: row terms cancel in softmax); 1024-2047 -> V
// (bias bv, stored transposed [v][s]). Grid 8x16xNB = 512 blocks = 2 rounds.
__global__ void __launch_bounds__(512, 1)
qkv_gemm_k(const __bf16* __restrict__ xb, const __bf16* __restrict__ Wcat,
           const float* __restrict__ bv, __bf16* __restrict__ Qb,
           __bf16* __restrict__ Vt) {
  size_t zo = (size_t)blockIdx.z * XB_STRIDE;
  xb += zo; Qb += zo; Vt += zo;
  __shared__ __bf16 lds[65536];
  f32x4 acc[8][4] = {};
  int m0 = blockIdx.y * 256, n0 = blockIdx.x * 256;
  gemm256_core(xb, 1024, m0, Wcat, 1024, n0, lds, acc);

  const int l = threadIdx.x & 63;
  const int w = threadIdx.x >> 6;
  const int wm = w >> 2, wn = w & 3;
  const int lr = l & 15;
  const int lg = (l >> 4) * 4;
#pragma unroll
  for (int am = 0; am < 8; am++) {
    int rs = m0 + wm * 128 + am * 16 + lg;
#pragma unroll
    for (int an = 0; an < 4; an++) {
      int col = n0 + wn * 64 + an * 16 + lr;
      if (col < 1024) {
#pragma unroll
        for (int r = 0; r < 4; r++)
          Qb[(rs + r) * 1024 + col] = (__bf16)acc[am][an][r];
      } else {
        float bias = bv[col - 1024];
        bf16x4 t4;
#pragma unroll
        for (int r = 0; r < 4; r++) t4[r] = (__bf16)(acc[am][an][r] + bias);
        *(bf16x4*)(Vt + (size_t)(col - 1024) * 4096 + rs) = t4;
      }
    }
  }
}

// ---------------------------------------------------------------------------
// QK^T (batched z): scores = Q'' @ xb^T (K projection eliminated).
__global__ void __launch_bounds__(512, 1)
qk_gemm_k(const __bf16* __restrict__ Qb, const __bf16* __restrict__ xb,
          float* __restrict__ sc) {
  if (blockIdx.x > blockIdx.y) return;
  size_t zo = (size_t)blockIdx.z * XB_STRIDE;
  Qb += zo; xb += zo;
  sc += (size_t)blockIdx.z * SC_STRIDE;
  __shared__ __bf16 lds[65536];
  f32x4 acc[8][4] = {};
  int m0 = blockIdx.y * 256, n0 = blockIdx.x * 256;
  gemm256_core(Qb, 1024, m0, xb, 1024, n0, lds, acc);

  const int l = threadIdx.x & 63;
  const int w = threadIdx.x >> 6;
  const int wm = w >> 2, wn = w & 3;
  const int lr = l & 15;
  const int lg = (l >> 4) * 4;
#pragma unroll
  for (int am = 0; am < 8; am++) {
    int rs = m0 + wm * 128 + am * 16 + lg;
#pragma unroll
    for (int an = 0; an < 4; an++) {
      int col = n0 + wn * 64 + an * 16 + lr;
#pragma unroll
      for (int r = 0; r < 4; r++)
        sc[(size_t)(rs + r) * 4096 + col] = acc[am][an][r];
    }
  }
}

// ---------------------------------------------------------------------------
// Row softmax, causal + alibi + column bias b_j (batched: blockIdx.y).
// P bf16 written in place into the second 8KB half of each 16KB score row.
__global__ void softmax_k(float* __restrict__ sc, const float* __restrict__ frame,
                          const float* __restrict__ alibi_p,
                          const float* __restrict__ bvec) {
  sc += (size_t)blockIdx.y * SC_STRIDE;
  bvec += (size_t)blockIdx.y * 4096;
  __shared__ float red[4];
  int s = blockIdx.x;
  float* srow = sc + (long)s * 4096;
  __bf16* prow = (__bf16*)(srow + 2048);
  int tid = threadIdx.x, lane = tid & 63, wid = tid >> 6;
  float sig = 1.0f / (1.0f + __expf(-alibi_p[0]));
  float fs = frame[s];
  int n = s + 1;
  int bound = ((s >> 7) + 1) << 7;
  int nv = (n + 3) >> 2;
  int bv = bound >> 2;

  const float4* srow4 = (const float4*)srow;
  const float4* fr4 = (const float4*)frame;
  const float4* bv4 = (const float4*)bvec;
  float4 vals[4];

  float mx = -3.4e38f;
#pragma unroll
  for (int it = 0; it < 4; it++) {
    int i = tid + it * 256;
    if (i < nv) {
      float4 v = srow4[i];
      float4 f = fr4[i];
      float4 bb = bv4[i];
      int t0 = i << 2;
      float a0 = (t0     < n) ? v.x + bb.x - sig * fabsf(f.x - fs) : -3.4e38f;
      float a1 = (t0 + 1 < n) ? v.y + bb.y - sig * fabsf(f.y - fs) : -3.4e38f;
      float a2 = (t0 + 2 < n) ? v.z + bb.z - sig * fabsf(f.z - fs) : -3.4e38f;
      float a3 = (t0 + 3 < n) ? v.w + bb.w - sig * fabsf(f.w - fs) : -3.4e38f;
      vals[it] = make_float4(a0, a1, a2, a3);
      mx = fmaxf(fmaxf(fmaxf(mx, a0), fmaxf(a1, a2)), a3);
    }
  }
#pragma unroll
  for (int o = 32; o; o >>= 1) mx = fmaxf(mx, __shfl_xor(mx, o, 64));
  if (lane == 0) red[wid] = mx;
  __syncthreads();
  mx = fmaxf(fmaxf(red[0], red[1]), fmaxf(red[2], red[3]));

  float sum = 0.0f;
#pragma unroll
  for (int it = 0; it < 4; it++) {
    int i = tid + it * 256;
    if (i < nv) {
      float4 v = vals[it];
      float e0 = __expf(v.x - mx), e1 = __expf(v.y - mx);
      float e2 = __expf(v.z - mx), e3 = __expf(v.w - mx);
      vals[it] = make_float4(e0, e1, e2, e3);
      sum += (e0 + e1) + (e2 + e3);
    }
  }
#pragma unroll
  for (int o = 32; o; o >>= 1) sum += __shfl_xor(sum, o, 64);
  __syncthreads();
  if (lane == 0) red[wid] = sum;
  __syncthreads();
  sum = red[0] + red[1] + red[2] + red[3];
  float inv = 1.0f / sum;

#pragma unroll
  for (int it = 0; it < 4; it++) {
    int i = tid + it * 256;
    if (i < bv) {
      bf16x4 o;
      if (i < nv) {
        float4 v = vals[it];
        o[0] = (__bf16)(v.x * inv); o[1] = (__bf16)(v.y * inv);
        o[2] = (__bf16)(v.z * inv); o[3] = (__bf16)(v.w * inv);
      } else {
        o[0] = o[1] = o[2] = o[3] = (__bf16)0.0f;
      }
      *(bf16x4*)(prow + (i << 2)) = o;
    }
  }
}

// ---------------------------------------------------------------------------
// PV (batched z): out[v][s] = sum_{t<=s} P[s,t] * Vt[v,t]; 128^2 core.
// Grid (32, 8, z): XCD grouping + depth reflection (round-9 win).
__global__ void pv_gemm_k(const __bf16* __restrict__ P, const __bf16* __restrict__ Vt,
                          float* __restrict__ outb) {
  int z = blockIdx.z;
  int mi = (z & 1) ? blockIdx.x : 31 - blockIdx.x;
  int n0 = blockIdx.y * 128;
  P    += (size_t)z * P_STRIDE;
  Vt   += (size_t)z * XB_STRIDE;
  outb += (size_t)z * OUT_STRIDE;
  __shared__ __bf16 As[2][4096], Bs[2][4096];
  f32x4 acc[4][4] = {};
  int m0 = mi * 128;
  gemm128_core(P, 8192, m0, Vt, 4096, n0, (m0 + 128) / 32, As, Bs, acc);

  const int lane = threadIdx.x & 63;
  const int wid = threadIdx.x >> 6;
  const int wr = wid >> 1, wc = wid & 1;
  const int lr = lane & 15;
  const int lg = (lane >> 4) * 4;
#pragma unroll
  for (int m = 0; m < 4; m++) {
    int rs = m0 + wr * 64 + m * 16 + lg;
#pragma unroll
    for (int n = 0; n < 4; n++) {
      int col = n0 + wc * 64 + n * 16 + lr;
      *(f32x4*)(outb + (long)col * 4096 + rs) = acc[m][n];
    }
  }
}

// ---------------------------------------------------------------------------

static inline char* align256(char* p) {
  return (char*)(((uintptr_t)p + 255) & ~(uintptr_t)255);
}

extern "C" void kernel_launch(void* const* d_in, const int* in_sizes, int n_in,
                              void* d_out, int out_size, void* d_ws, size_t ws_size,
                              hipStream_t stream) {
  const float* input = (const float*)d_in[0];   // [4][1024][4096]
  const float* frame = (const float*)d_in[1];   // [4096]
  const float* Wq = (const float*)d_in[2];
  const float* bq = (const float*)d_in[3];
  const float* Wk = (const float*)d_in[4];
  const float* bk = (const float*)d_in[5];      // unused: k-bias terms cancel / fold
  const float* Wv = (const float*)d_in[6];
  const float* bv = (const float*)d_in[7];
  const float* alibi = (const float*)d_in[8];
  float* out = (float*)d_out;                   // [4][2048][4096]
  (void)bk;

  const size_t NEED_BATCHED = (size_t)12 * 1024 * 1024 + (1 << 20) +
                              3 * (4 * XB_STRIDE * 2) + 4 * SC_STRIDE * 4 + 4096;
  int NB = (ws_size >= NEED_BATCHED) ? 4 : 1;

  char* p = (char*)d_ws;
  __bf16* Wq_nb = (__bf16*)p;  p += (size_t)1024 * 1024 * 2;
  __bf16* Wk_nb = (__bf16*)p;  p += (size_t)1024 * 1024 * 2;
  __bf16* Wcat  = (__bf16*)p;  p += (size_t)2048 * 1024 * 2;   // rows 0-1023: Mt, 1024+: Wv^T
  float* wtld   = (float*)p;   p += 1024 * 4;
  float* bvec   = (float*)p;   p += NB * 4096 * 4;             p = align256(p);
  __bf16* xb = (__bf16*)p;  p += NB * XB_STRIDE * 2;           p = align256(p);
  __bf16* Qb = (__bf16*)p;  p += NB * XB_STRIDE * 2;           p = align256(p);
  __bf16* Vt = (__bf16*)p;  p += NB * XB_STRIDE * 2;           p = align256(p);
  float* sc = (float*)p;    // NB x [4096][4096] fp32; P aliased into row halves

  convert_w_k<<<dim3(1024, 2), 256, 0, stream>>>(Wq, Wk, Wq_nb, Wk_nb);
  transpose_wv_k<<<dim3(32, 32), dim3(32, 8), 0, stream>>>(Wv, Wcat);
  wqwk_k<<<dim3(8, 8), 256, 0, stream>>>(Wk_nb, Wq_nb, Wcat);
  wtld_k<<<1024, 256, 0, stream>>>(Wk, bq, wtld);
  copy_in_k<<<16384, 256, 0, stream>>>((const float4*)input, (float4*)out);

  for (int b0 = 0; b0 < 4; b0 += NB) {
    const float* inb = input + (size_t)b0 * XB_STRIDE;
    float* outb = out + (size_t)b0 * OUT_STRIDE + (size_t)1024 * 4096;
    transpose_x_k<<<dim3(128, 32, NB), dim3(32, 8), 0, stream>>>(inb, xb);
    bvec_k<<<dim3(4096, NB), 256, 0, stream>>>(xb, wtld, bvec);
    qkv_gemm_k<<<dim3(8, 16, NB), 512, 0, stream>>>(xb, Wcat, bv, Qb, Vt);
    qk_gemm_k<<<dim3(16, 16, NB), 512, 0, stream>>>(Qb, xb, sc);
    softmax_k<<<dim3(4096, NB), 256, 0, stream>>>(sc, frame, alibi, bvec);
    pv_gemm_k<<<dim3(32, 8, NB), 256, 0, stream>>>((const __bf16*)((char*)sc + 8192), Vt, outb);
  }
}

// Round 12
// 456.984 us; speedup vs baseline: 1.0075x; 1.0075x over previous
//
#include <hip/hip_runtime.h>
#include <cstdint>

#define AS1 __attribute__((address_space(1)))
#define AS3 __attribute__((address_space(3)))

typedef __bf16 bf16x8 __attribute__((ext_vector_type(8)));
typedef __bf16 bf16x4 __attribute__((ext_vector_type(4)));
typedef float  f32x4  __attribute__((ext_vector_type(4)));

// Per-batch element strides
#define XB_STRIDE   4194304ul   // 4096*1024 bf16 (also Qb, Vt, input-slice fp32)
#define SC_STRIDE   16777216ul  // 4096*4096 fp32
#define P_STRIDE    33554432ul  // score batch stride in bf16 units
#define OUT_STRIDE  8388608ul   // 2048*4096 fp32

// ---------------------------------------------------------------------------
// ALGEBRA: scores = (XWq+bq)(XWk+bk)^T / 32 = X Mt^T... (see round 11)
// Row terms cancel in softmax; only b_j = x_j · (Wk bq)/32 survives.
// Q'' = X·Mt with Mt = Wk Wq_s^T; scores = Q''·X^T + b_j (+ alibi).
// ---------------------------------------------------------------------------

// input slice [1024][4096] fp32 -> xb [4096][1024] bf16 (tiled transpose),
// FUSED with the identity copy into the output top-half (saves a dispatch +
// a redundant 64MB read). Batched z.
__global__ void transpose_x_k(const float* __restrict__ in, __bf16* __restrict__ out,
                              float* __restrict__ outtop) {
  in     += (size_t)blockIdx.z * XB_STRIDE;
  out    += (size_t)blockIdx.z * XB_STRIDE;
  outtop += (size_t)blockIdx.z * OUT_STRIDE;
  __shared__ float t[32][33];
  int s0 = blockIdx.x * 32, c0 = blockIdx.y * 32;
  int tx = threadIdx.x, ty = threadIdx.y;
#pragma unroll
  for (int i = 0; i < 4; i++) {
    int idx = (c0 + ty + i * 8) * 4096 + s0 + tx;
    float v = in[idx];
    t[ty + i * 8][tx] = v;
    outtop[idx] = v;                       // fp32 copy to out[b][c][s], c<1024
  }
  __syncthreads();
#pragma unroll
  for (int i = 0; i < 4; i++)
    out[(s0 + ty + i * 8) * 1024 + c0 + tx] = (__bf16)t[tx][ty + i * 8];
}

// Wq/Wk fp32 [1024][1024] -> bf16 copies (row-major, Wq scaled 1/32)
__global__ void convert_w_k(const float* __restrict__ Wq, const float* __restrict__ Wk,
                            __bf16* __restrict__ Wq_nb, __bf16* __restrict__ Wk_nb) {
  int row = blockIdx.x, sel = blockIdx.y, t = threadIdx.x;
  const float* src = (sel ? Wk : Wq) + (size_t)row * 1024;
  __bf16* dst = (sel ? Wk_nb : Wq_nb) + (size_t)row * 1024;
  float scale = sel ? 1.0f : 0.03125f;
  float4 v = ((const float4*)src)[t];
  bf16x4 o;
  o[0] = (__bf16)(v.x * scale); o[1] = (__bf16)(v.y * scale);
  o[2] = (__bf16)(v.z * scale); o[3] = (__bf16)(v.w * scale);
  ((bf16x4*)dst)[t] = o;
}

// Wv [1024][1024] fp32 -> Wcat rows [1024,2048) bf16 transposed ([n][c])
__global__ void transpose_wv_k(const float* __restrict__ Wv, __bf16* __restrict__ Wcat) {
  __shared__ float t[32][33];
  int n0 = blockIdx.x * 32, c0 = blockIdx.y * 32;
  int tx = threadIdx.x, ty = threadIdx.y;
#pragma unroll
  for (int i = 0; i < 4; i++)
    t[ty + i * 8][tx] = Wv[(c0 + ty + i * 8) * 1024 + n0 + tx];
  __syncthreads();
#pragma unroll
  for (int i = 0; i < 4; i++)
    Wcat[(size_t)(1024 + n0 + ty + i * 8) * 1024 + c0 + tx] = (__bf16)t[tx][ty + i * 8];
}

// wtld[c] = (1/32) * sum_n Wk[c][n] * bq[n]   (score scale folded in)
__global__ void wtld_k(const float* __restrict__ Wk, const float* __restrict__ bq,
                       float* __restrict__ wtld) {
  __shared__ float red[4];
  int c = blockIdx.x, tid = threadIdx.x, lane = tid & 63, wid = tid >> 6;
  float4 w = ((const float4*)(Wk + (size_t)c * 1024))[tid];
  float4 b = ((const float4*)bq)[tid];
  float s = w.x * b.x + w.y * b.y + w.z * b.z + w.w * b.w;
#pragma unroll
  for (int o = 32; o; o >>= 1) s += __shfl_xor(s, o, 64);
  if (lane == 0) red[wid] = s;
  __syncthreads();
  if (tid == 0) wtld[c] = (red[0] + red[1] + red[2] + red[3]) * 0.03125f;
}

// bvec[z][j] = xb[z][j,:] . wtld — wave-per-row, 64 rows/block (grid 64 x NB).
// Lane preloads its 16 wtld values; each row is a coalesced 32B/lane read.
__global__ void bvec_k(const __bf16* __restrict__ xb, const float* __restrict__ wtld,
                       float* __restrict__ bvec) {
  xb += (size_t)blockIdx.y * XB_STRIDE;
  bvec += (size_t)blockIdx.y * 4096;
  int tid = threadIdx.x, lane = tid & 63, w = tid >> 6;
  const float4* wt4 = (const float4*)wtld;
  float4 w0 = wt4[lane * 4], w1 = wt4[lane * 4 + 1];
  float4 w2 = wt4[lane * 4 + 2], w3 = wt4[lane * 4 + 3];
  int base = blockIdx.x * 64 + w;
#pragma unroll
  for (int i = 0; i < 16; i++) {
    int j = base + i * 4;
    const bf16x8* row = (const bf16x8*)(xb + (size_t)j * 1024);
    bf16x8 v0 = row[lane * 2], v1 = row[lane * 2 + 1];
    float s = (float)v0[0] * w0.x + (float)v0[1] * w0.y + (float)v0[2] * w0.z + (float)v0[3] * w0.w
            + (float)v0[4] * w1.x + (float)v0[5] * w1.y + (float)v0[6] * w1.z + (float)v0[7] * w1.w
            + (float)v1[0] * w2.x + (float)v1[1] * w2.y + (float)v1[2] * w2.z + (float)v1[3] * w2.w
            + (float)v1[4] * w3.x + (float)v1[5] * w3.y + (float)v1[6] * w3.z + (float)v1[7] * w3.w;
#pragma unroll
    for (int o = 32; o; o >>= 1) s += __shfl_xor(s, o, 64);
    if (lane == 0) bvec[j] = s;
  }
}

// ---------------------------------------------------------------------------
// 128x128 depth-2 pipelined core (round-6): used by PV and the Mt precompute.
__device__ __forceinline__ void gemm128_core(const __bf16* __restrict__ A, int lda, int m0,
                                             const __bf16* __restrict__ B, int ldb, int n0,
                                             int nt, __bf16 (*As)[4096], __bf16 (*Bs)[4096],
                                             f32x4 acc[4][4]) {
  const int tid = threadIdx.x;
  const int lane = tid & 63;
  const int wid = tid >> 6;
  const int wr = wid >> 1, wc = wid & 1;
  const int lr = lane & 15;
  const int lk = (lane >> 4) << 3;
  const int srow = tid >> 2;
  const int skq = (tid & 3) << 3;
  const __bf16* ga = A + (long)(m0 + srow) * lda + skq;
  const __bf16* gb = B + (long)(n0 + srow) * ldb + skq;

#define STAGE(t, j) do {                                                                                             \
    int k0_ = (t) * 32;                                                                                              \
    __builtin_amdgcn_global_load_lds((const AS1 void*)(ga + k0_),            (AS3 void*)(As[j] + tid * 8),        16, 0, 0); \
    __builtin_amdgcn_global_load_lds((const AS1 void*)(ga + k0_ + 64 * lda), (AS3 void*)(As[j] + tid * 8 + 2048), 16, 0, 0); \
    __builtin_amdgcn_global_load_lds((const AS1 void*)(gb + k0_),            (AS3 void*)(Bs[j] + tid * 8),        16, 0, 0); \
    __builtin_amdgcn_global_load_lds((const AS1 void*)(gb + k0_ + 64 * ldb), (AS3 void*)(Bs[j] + tid * 8 + 2048), 16, 0, 0); \
  } while (0)

  STAGE(0, 0);
  if (nt > 1) STAGE(1, 1);

  for (int t = 0; t < nt; ++t) {
    const int j = t & 1;
    if (t + 1 < nt) asm volatile("s_waitcnt vmcnt(4)" ::: "memory");
    else            asm volatile("s_waitcnt vmcnt(0)" ::: "memory");
    __builtin_amdgcn_s_barrier();
    __builtin_amdgcn_sched_barrier(0);

    bf16x8 af[4], bfr[4];
#pragma unroll
    for (int m = 0; m < 4; m++)
      af[m] = *(const bf16x8*)(As[j] + (wr * 64 + m * 16 + lr) * 32 + lk);
#pragma unroll
    for (int n = 0; n < 4; n++)
      bfr[n] = *(const bf16x8*)(Bs[j] + (wc * 64 + n * 16 + lr) * 32 + lk);
#pragma unroll
    for (int m = 0; m < 4; m++)
#pragma unroll
      for (int n = 0; n < 4; n++)
        acc[m][n] = __builtin_amdgcn_mfma_f32_16x16x32_bf16(af[m], bfr[n], acc[m][n], 0, 0, 0);

    asm volatile("s_waitcnt lgkmcnt(0)" ::: "memory");
    __builtin_amdgcn_sched_barrier(0);
    __builtin_amdgcn_s_barrier();
    __builtin_amdgcn_sched_barrier(0);
    if (t + 2 < nt) STAGE(t + 2, j);
  }
#undef STAGE
}

// Mt = Wk Wq_s^T into Wcat rows [0,1024): Mt[c'][c] = sum_n Wk[c'][n] Wq_s[c][n]
__global__ void wqwk_k(const __bf16* __restrict__ Wk_nb, const __bf16* __restrict__ Wq_nb,
                       __bf16* __restrict__ Wcat) {
  __shared__ __bf16 As[2][4096], Bs[2][4096];
  f32x4 acc[4][4] = {};
  int m0 = blockIdx.y * 128, n0 = blockIdx.x * 128;
  gemm128_core(Wk_nb, 1024, m0, Wq_nb, 1024, n0, 32, As, Bs, acc);

  const int lane = threadIdx.x & 63;
  const int wid = threadIdx.x >> 6;
  const int wr = wid >> 1, wc = wid & 1;
  const int lr = lane & 15;
  const int lg = (lane >> 4) * 4;
#pragma unroll
  for (int m = 0; m < 4; m++) {
    int rs = m0 + wr * 64 + m * 16 + lg;
#pragma unroll
    for (int n = 0; n < 4; n++) {
      int col = n0 + wc * 64 + n * 16 + lr;
#pragma unroll
      for (int r = 0; r < 4; r++)
        Wcat[(size_t)(rs + r) * 1024 + col] = (__bf16)acc[m][n][r];
    }
  }
}

// ---------------------------------------------------------------------------
// 256x256 BK=64 streaming GEMM core (round 10; bank-conflict-free swizzle,
// counted vmcnt, 2 barriers/K-tile). Unchanged.
// ---------------------------------------------------------------------------
template<int MH, int NH>
__device__ __forceinline__ void mf_quad(f32x4 (&acc)[8][4], bf16x8 (&aR)[4][2],
                                        bf16x8 (&br)[2][2]) {
#pragma unroll
  for (int q = 0; q < 4; q++)
#pragma unroll
    for (int r = 0; r < 2; r++) {
      acc[MH * 4 + q][NH * 2 + r] = __builtin_amdgcn_mfma_f32_16x16x32_bf16(
          aR[q][0], br[r][0], acc[MH * 4 + q][NH * 2 + r], 0, 0, 0);
      acc[MH * 4 + q][NH * 2 + r] = __builtin_amdgcn_mfma_f32_16x16x32_bf16(
          aR[q][1], br[r][1], acc[MH * 4 + q][NH * 2 + r], 0, 0, 0);
    }
}

__device__ __forceinline__ void gemm256_core(const __bf16* __restrict__ A, int lda, int m0,
                                             const __bf16* __restrict__ B, int ldb, int n0,
                                             __bf16* lds, f32x4 (&acc)[8][4]) {
  const int tid = threadIdx.x;
  const int l = tid & 63;
  const int w = tid >> 6;
  const int wm = w >> 2, wn = w & 3;
  const int lr = l & 15, kg = l >> 4;
  const int lrow = l >> 3;
  const int scol = ((l & 7) ^ lrow) << 3;
  const int xorv = (lr & 7) << 4;
  const int cc0 = (kg << 4) ^ xorv;
  const int cc1 = (64 | (kg << 4)) ^ xorv;
  const int ch = w * 2;
  const char* ldsA = (const char*)lds + wm * 16384;
  const char* ldsB = (const char*)lds + 32768 + (wn >> 1) * 16384;
  const int browb = (wn & 1) * 64;

#define STG8(PTR, LD, BASE0, H, TT, JB, OPOFF) do {                                              \
    const __bf16* sp_ = (PTR) + (size_t)((BASE0) + (H) * 128 + ch * 8 + lrow) * (LD) +           \
                        (TT) * 64 + scol;                                                        \
    __bf16* dp_ = lds + ((JB) * 32768 + (OPOFF) + (H) * 8192 + ch * 512);                        \
    __builtin_amdgcn_global_load_lds((const AS1 void*)sp_,                   (AS3 void*)dp_,         16, 0, 0); \
    __builtin_amdgcn_global_load_lds((const AS1 void*)(sp_ + (size_t)8 * (LD)), (AS3 void*)(dp_ + 512), 16, 0, 0); \
  } while (0)
#define STGA(H, TT, JB) STG8(A, lda, m0, H, TT, JB, 0)
#define STGB(H, TT, JB) STG8(B, ldb, n0, H, TT, JB, 16384)
#define LDAF(dst, MH_, Q_) do {                                                                  \
    const char* p_ = ldsA + jbyte + ((MH_) * 64 + (Q_) * 16 + lr) * 128;                         \
    (dst)[0] = *(const bf16x8*)(p_ + cc0);                                                       \
    (dst)[1] = *(const bf16x8*)(p_ + cc1);                                                       \
  } while (0)
#define LDBF(dst, NH_, R_) do {                                                                  \
    const char* p_ = ldsB + jbyte + (browb + ((NH_) * 2 + (R_)) * 16 + lr) * 128;                \
    (dst)[0] = *(const bf16x8*)(p_ + cc0);                                                       \
    (dst)[1] = *(const bf16x8*)(p_ + cc1);                                                       \
  } while (0)

  STGA(0, 0, 0); STGA(1, 0, 0); STGB(0, 0, 0); STGB(1, 0, 0);
  STGB(0, 1, 1); STGA(0, 1, 1);
  asm volatile("s_waitcnt vmcnt(4)" ::: "memory");
  __builtin_amdgcn_sched_barrier(0);
  __builtin_amdgcn_s_barrier();

  bf16x8 aR[4][2], b0r[2][2], b1r[2][2];
  for (int t = 0; t < 16; ++t) {
    const int j = t & 1, jo = j ^ 1;
    const int jbyte = j * 65536;

#pragma unroll
    for (int q = 0; q < 4; q++) LDAF(aR[q], 0, q);
#pragma unroll
    for (int r = 0; r < 2; r++) LDBF(b0r[r], 0, r);
#pragma unroll
    for (int r = 0; r < 2; r++) LDBF(b1r[r], 1, r);
    if (t < 15) { STGA(1, t + 1, jo); STGB(1, t + 1, jo); }

    __builtin_amdgcn_s_setprio(1);
    mf_quad<0, 0>(acc, aR, b0r);
    mf_quad<0, 1>(acc, aR, b1r);
    __builtin_amdgcn_s_setprio(0);

#pragma unroll
    for (int q = 0; q < 4; q++) LDAF(aR[q], 1, q);
    __builtin_amdgcn_s_setprio(1);
    mf_quad<1, 1>(acc, aR, b1r);
    __builtin_amdgcn_s_setprio(0);

    asm volatile("s_waitcnt lgkmcnt(0)" ::: "memory");
    __builtin_amdgcn_sched_barrier(0);
    __builtin_amdgcn_s_barrier();
    if (t < 14) { STGB(0, t + 2, j); STGA(0, t + 2, j); }

    __builtin_amdgcn_s_setprio(1);
    mf_quad<1, 0>(acc, aR, b0r);
    __builtin_amdgcn_s_setprio(0);

    if (t < 14) asm volatile("s_waitcnt vmcnt(4)" ::: "memory");
    else        asm volatile("s_waitcnt vmcnt(0)" ::: "memory");
    __builtin_amdgcn_sched_barrier(0);
    __builtin_amdgcn_s_barrier();
  }
#undef STG8
#undef STGA
#undef STGB
#undef LDAF
#undef LDBF
}

// ---------------------------------------------------------------------------
// Q''/V projection (batched z): [4096 x 2048] = xb @ Wcat^T.
__global__ void __launch_bounds__(512, 1)
qkv_gemm_k(const __bf16* __restrict__ xb, const __bf16* __restrict__ Wcat,
           const float* __restrict__ bv, __bf16* __restrict__ Qb,
           __bf16* __restrict__ Vt) {
  size_t zo = (size_t)blockIdx.z * XB_STRIDE;
  xb += zo; Qb += zo; Vt += zo;
  __shared__ __bf16 lds[65536];
  f32x4 acc[8][4] = {};
  int m0 = blockIdx.y * 256, n0 = blockIdx.x * 256;
  gemm256_core(xb, 1024, m0, Wcat, 1024, n0, lds, acc);

  const int l = threadIdx.x & 63;
  const int w = threadIdx.x >> 6;
  const int wm = w >> 2, wn = w & 3;
  const int lr = l & 15;
  const int lg = (l >> 4) * 4;
#pragma unroll
  for (int am = 0; am < 8; am++) {
    int rs = m0 + wm * 128 + am * 16 + lg;
#pragma unroll
    for (int an = 0; an < 4; an++) {
      int col = n0 + wn * 64 + an * 16 + lr;
      if (col < 1024) {
#pragma unroll
        for (int r = 0; r < 4; r++)
          Qb[(rs + r) * 1024 + col] = (__bf16)acc[am][an][r];
      } else {
        float bias = bv[col - 1024];
        bf16x4 t4;
#pragma unroll
        for (int r = 0; r < 4; r++) t4[r] = (__bf16)(acc[am][an][r] + bias);
        *(bf16x4*)(Vt + (size_t)(col - 1024) * 4096 + rs) = t4;
      }
    }
  }
}

// ---------------------------------------------------------------------------
// QK^T (batched z): scores = Q'' @ xb^T (K projection eliminated).
__global__ void __launch_bounds__(512, 1)
qk_gemm_k(const __bf16* __restrict__ Qb, const __bf16* __restrict__ xb,
          float* __restrict__ sc) {
  if (blockIdx.x > blockIdx.y) return;
  size_t zo = (size_t)blockIdx.z * XB_STRIDE;
  Qb += zo; xb += zo;
  sc += (size_t)blockIdx.z * SC_STRIDE;
  __shared__ __bf16 lds[65536];
  f32x4 acc[8][4] = {};
  int m0 = blockIdx.y * 256, n0 = blockIdx.x * 256;
  gemm256_core(Qb, 1024, m0, xb, 1024, n0, lds, acc);

  const int l = threadIdx.x & 63;
  const int w = threadIdx.x >> 6;
  const int wm = w >> 2, wn = w & 3;
  const int lr = l & 15;
  const int lg = (l >> 4) * 4;
#pragma unroll
  for (int am = 0; am < 8; am++) {
    int rs = m0 + wm * 128 + am * 16 + lg;
#pragma unroll
    for (int an = 0; an < 4; an++) {
      int col = n0 + wn * 64 + an * 16 + lr;
#pragma unroll
      for (int r = 0; r < 4; r++)
        sc[(size_t)(rs + r) * 4096 + col] = acc[am][an][r];
    }
  }
}

// ---------------------------------------------------------------------------
// Row softmax, causal + alibi + column bias b_j (batched: blockIdx.y).
__global__ void softmax_k(float* __restrict__ sc, const float* __restrict__ frame,
                          const float* __restrict__ alibi_p,
                          const float* __restrict__ bvec) {
  sc += (size_t)blockIdx.y * SC_STRIDE;
  bvec += (size_t)blockIdx.y * 4096;
  __shared__ float red[4];
  int s = blockIdx.x;
  float* srow = sc + (long)s * 4096;
  __bf16* prow = (__bf16*)(srow + 2048);
  int tid = threadIdx.x, lane = tid & 63, wid = tid >> 6;
  float sig = 1.0f / (1.0f + __expf(-alibi_p[0]));
  float fs = frame[s];
  int n = s + 1;
  int bound = ((s >> 7) + 1) << 7;
  int nv = (n + 3) >> 2;
  int bv = bound >> 2;

  const float4* srow4 = (const float4*)srow;
  const float4* fr4 = (const float4*)frame;
  const float4* bv4 = (const float4*)bvec;
  float4 vals[4];

  float mx = -3.4e38f;
#pragma unroll
  for (int it = 0; it < 4; it++) {
    int i = tid + it * 256;
    if (i < nv) {
      float4 v = srow4[i];
      float4 f = fr4[i];
      float4 bb = bv4[i];
      int t0 = i << 2;
      float a0 = (t0     < n) ? v.x + bb.x - sig * fabsf(f.x - fs) : -3.4e38f;
      float a1 = (t0 + 1 < n) ? v.y + bb.y - sig * fabsf(f.y - fs) : -3.4e38f;
      float a2 = (t0 + 2 < n) ? v.z + bb.z - sig * fabsf(f.z - fs) : -3.4e38f;
      float a3 = (t0 + 3 < n) ? v.w + bb.w - sig * fabsf(f.w - fs) : -3.4e38f;
      vals[it] = make_float4(a0, a1, a2, a3);
      mx = fmaxf(fmaxf(fmaxf(mx, a0), fmaxf(a1, a2)), a3);
    }
  }
#pragma unroll
  for (int o = 32; o; o >>= 1) mx = fmaxf(mx, __shfl_xor(mx, o, 64));
  if (lane == 0) red[wid] = mx;
  __syncthreads();
  mx = fmaxf(fmaxf(red[0], red[1]), fmaxf(red[2], red[3]));

  float sum = 0.0f;
#pragma unroll
  for (int it = 0; it < 4; it++) {
    int i = tid + it * 256;
    if (i < nv) {
      float4 v = vals[it];
      float e0 = __expf(v.x - mx), e1 = __expf(v.y - mx);
      float e2 = __expf(v.z - mx), e3 = __expf(v.w - mx);
      vals[it] = make_float4(e0, e1, e2, e3);
      sum += (e0 + e1) + (e2 + e3);
    }
  }
#pragma unroll
  for (int o = 32; o; o >>= 1) sum += __shfl_xor(sum, o, 64);
  __syncthreads();
  if (lane == 0) red[wid] = sum;
  __syncthreads();
  sum = red[0] + red[1] + red[2] + red[3];
  float inv = 1.0f / sum;

#pragma unroll
  for (int it = 0; it < 4; it++) {
    int i = tid + it * 256;
    if (i < bv) {
      bf16x4 o;
      if (i < nv) {
        float4 v = vals[it];
        o[0] = (__bf16)(v.x * inv); o[1] = (__bf16)(v.y * inv);
        o[2] = (__bf16)(v.z * inv); o[3] = (__bf16)(v.w * inv);
      } else {
        o[0] = o[1] = o[2] = o[3] = (__bf16)0.0f;
      }
      *(bf16x4*)(prow + (i << 2)) = o;
    }
  }
}

// ---------------------------------------------------------------------------
// PV (batched z): out[v][s] = sum_{t<=s} P[s,t] * Vt[v,t]; 128^2 core.
// Grid (32, 8, z): XCD grouping + depth reflection (round-9 win).
__global__ void pv_gemm_k(const __bf16* __restrict__ P, const __bf16* __restrict__ Vt,
                          float* __restrict__ outb) {
  int z = blockIdx.z;
  int mi = (z & 1) ? blockIdx.x : 31 - blockIdx.x;
  int n0 = blockIdx.y * 128;
  P    += (size_t)z * P_STRIDE;
  Vt   += (size_t)z * XB_STRIDE;
  outb += (size_t)z * OUT_STRIDE;
  __shared__ __bf16 As[2][4096], Bs[2][4096];
  f32x4 acc[4][4] = {};
  int m0 = mi * 128;
  gemm128_core(P, 8192, m0, Vt, 4096, n0, (m0 + 128) / 32, As, Bs, acc);

  const int lane = threadIdx.x & 63;
  const int wid = threadIdx.x >> 6;
  const int wr = wid >> 1, wc = wid & 1;
  const int lr = lane & 15;
  const int lg = (lane >> 4) * 4;
#pragma unroll
  for (int m = 0; m < 4; m++) {
    int rs = m0 + wr * 64 + m * 16 + lg;
#pragma unroll
    for (int n = 0; n < 4; n++) {
      int col = n0 + wc * 64 + n * 16 + lr;
      *(f32x4*)(outb + (long)col * 4096 + rs) = acc[m][n];
    }
  }
}

// ---------------------------------------------------------------------------

static inline char* align256(char* p) {
  return (char*)(((uintptr_t)p + 255) & ~(uintptr_t)255);
}

extern "C" void kernel_launch(void* const* d_in, const int* in_sizes, int n_in,
                              void* d_out, int out_size, void* d_ws, size_t ws_size,
                              hipStream_t stream) {
  const float* input = (const float*)d_in[0];   // [4][1024][4096]
  const float* frame = (const float*)d_in[1];   // [4096]
  const float* Wq = (const float*)d_in[2];
  const float* bq = (const float*)d_in[3];
  const float* Wk = (const float*)d_in[4];
  const float* bk = (const float*)d_in[5];      // unused: k-bias terms cancel in softmax
  const float* Wv = (const float*)d_in[6];
  const float* bv = (const float*)d_in[7];
  const float* alibi = (const float*)d_in[8];
  float* out = (float*)d_out;                   // [4][2048][4096]
  (void)bk;

  const size_t NEED_BATCHED = (size_t)12 * 1024 * 1024 + (1 << 20) +
                              3 * (4 * XB_STRIDE * 2) + 4 * SC_STRIDE * 4 + 4096;
  int NB = (ws_size >= NEED_BATCHED) ? 4 : 1;

  char* p = (char*)d_ws;
  __bf16* Wq_nb = (__bf16*)p;  p += (size_t)1024 * 1024 * 2;
  __bf16* Wk_nb = (__bf16*)p;  p += (size_t)1024 * 1024 * 2;
  __bf16* Wcat  = (__bf16*)p;  p += (size_t)2048 * 1024 * 2;   // rows 0-1023: Mt, 1024+: Wv^T
  float* wtld   = (float*)p;   p += 1024 * 4;
  float* bvec   = (float*)p;   p += NB * 4096 * 4;             p = align256(p);
  __bf16* xb = (__bf16*)p;  p += NB * XB_STRIDE * 2;           p = align256(p);
  __bf16* Qb = (__bf16*)p;  p += NB * XB_STRIDE * 2;           p = align256(p);
  __bf16* Vt = (__bf16*)p;  p += NB * XB_STRIDE * 2;           p = align256(p);
  float* sc = (float*)p;    // NB x [4096][4096] fp32; P aliased into row halves

  convert_w_k<<<dim3(1024, 2), 256, 0, stream>>>(Wq, Wk, Wq_nb, Wk_nb);
  transpose_wv_k<<<dim3(32, 32), dim3(32, 8), 0, stream>>>(Wv, Wcat);
  wqwk_k<<<dim3(8, 8), 256, 0, stream>>>(Wk_nb, Wq_nb, Wcat);
  wtld_k<<<1024, 256, 0, stream>>>(Wk, bq, wtld);

  for (int b0 = 0; b0 < 4; b0 += NB) {
    const float* inb = input + (size_t)b0 * XB_STRIDE;
    float* outtop = out + (size_t)b0 * OUT_STRIDE;
    float* outb = outtop + (size_t)1024 * 4096;
    transpose_x_k<<<dim3(128, 32, NB), dim3(32, 8), 0, stream>>>(inb, xb, outtop);
    bvec_k<<<dim3(64, NB), 256, 0, stream>>>(xb, wtld, bvec);
    qkv_gemm_k<<<dim3(8, 16, NB), 512, 0, stream>>>(xb, Wcat, bv, Qb, Vt);
    qk_gemm_k<<<dim3(16, 16, NB), 512, 0, stream>>>(Qb, xb, sc);
    softmax_k<<<dim3(4096, NB), 256, 0, stream>>>(sc, frame, alibi, bvec);
    pv_gemm_k<<<dim3(32, 8, NB), 256, 0, stream>>>((const __bf16*)((char*)sc + 8192), Vt, outb);
  }
}

// Round 13
// 452.122 us; speedup vs baseline: 1.0183x; 1.0108x over previous
//
#include <hip/hip_runtime.h>
#include <cstdint>

#define AS1 __attribute__((address_space(1)))
#define AS3 __attribute__((address_space(3)))

typedef __bf16 bf16x8 __attribute__((ext_vector_type(8)));
typedef __bf16 bf16x4 __attribute__((ext_vector_type(4)));
typedef float  f32x4  __attribute__((ext_vector_type(4)));

// Per-batch element strides
#define XB_STRIDE   4194304ul   // 4096*1024 bf16 (also Qb, Vt, input-slice fp32)
#define SC_STRIDE   16777216ul  // 4096*4096 fp32
#define P_STRIDE    33554432ul  // score batch stride in bf16 units
#define OUT_STRIDE  8388608ul   // 2048*4096 fp32

// ---------------------------------------------------------------------------
// ALGEBRA: scores = (XWq+bq)(XWk+bk)^T / 32; row terms cancel in softmax.
// Q'' = X·Mt (Mt = Wk Wq_s^T); scores = Q''·X^T + b_j (+ alibi), b_j = x_j·(Wk bq)/32.
// ---------------------------------------------------------------------------

// input slice -> xb bf16 transpose, fused with fp32 copy into output top-half.
__global__ void transpose_x_k(const float* __restrict__ in, __bf16* __restrict__ out,
                              float* __restrict__ outtop) {
  in     += (size_t)blockIdx.z * XB_STRIDE;
  out    += (size_t)blockIdx.z * XB_STRIDE;
  outtop += (size_t)blockIdx.z * OUT_STRIDE;
  __shared__ float t[32][33];
  int s0 = blockIdx.x * 32, c0 = blockIdx.y * 32;
  int tx = threadIdx.x, ty = threadIdx.y;
#pragma unroll
  for (int i = 0; i < 4; i++) {
    int idx = (c0 + ty + i * 8) * 4096 + s0 + tx;
    float v = in[idx];
    t[ty + i * 8][tx] = v;
    outtop[idx] = v;
  }
  __syncthreads();
#pragma unroll
  for (int i = 0; i < 4; i++)
    out[(s0 + ty + i * 8) * 1024 + c0 + tx] = (__bf16)t[tx][ty + i * 8];
}

// Wq/Wk fp32 -> bf16 (Wq scaled 1/32)
__global__ void convert_w_k(const float* __restrict__ Wq, const float* __restrict__ Wk,
                            __bf16* __restrict__ Wq_nb, __bf16* __restrict__ Wk_nb) {
  int row = blockIdx.x, sel = blockIdx.y, t = threadIdx.x;
  const float* src = (sel ? Wk : Wq) + (size_t)row * 1024;
  __bf16* dst = (sel ? Wk_nb : Wq_nb) + (size_t)row * 1024;
  float scale = sel ? 1.0f : 0.03125f;
  float4 v = ((const float4*)src)[t];
  bf16x4 o;
  o[0] = (__bf16)(v.x * scale); o[1] = (__bf16)(v.y * scale);
  o[2] = (__bf16)(v.z * scale); o[3] = (__bf16)(v.w * scale);
  ((bf16x4*)dst)[t] = o;
}

// Wv fp32 -> Wcat rows [1024,2048) bf16 transposed ([n][c])
__global__ void transpose_wv_k(const float* __restrict__ Wv, __bf16* __restrict__ Wcat) {
  __shared__ float t[32][33];
  int n0 = blockIdx.x * 32, c0 = blockIdx.y * 32;
  int tx = threadIdx.x, ty = threadIdx.y;
#pragma unroll
  for (int i = 0; i < 4; i++)
    t[ty + i * 8][tx] = Wv[(c0 + ty + i * 8) * 1024 + n0 + tx];
  __syncthreads();
#pragma unroll
  for (int i = 0; i < 4; i++)
    Wcat[(size_t)(1024 + n0 + ty + i * 8) * 1024 + c0 + tx] = (__bf16)t[tx][ty + i * 8];
}

// wtld[c] = (1/32) * sum_n Wk[c][n] * bq[n]
__global__ void wtld_k(const float* __restrict__ Wk, const float* __restrict__ bq,
                       float* __restrict__ wtld) {
  __shared__ float red[4];
  int c = blockIdx.x, tid = threadIdx.x, lane = tid & 63, wid = tid >> 6;
  float4 w = ((const float4*)(Wk + (size_t)c * 1024))[tid];
  float4 b = ((const float4*)bq)[tid];
  float s = w.x * b.x + w.y * b.y + w.z * b.z + w.w * b.w;
#pragma unroll
  for (int o = 32; o; o >>= 1) s += __shfl_xor(s, o, 64);
  if (lane == 0) red[wid] = s;
  __syncthreads();
  if (tid == 0) wtld[c] = (red[0] + red[1] + red[2] + red[3]) * 0.03125f;
}

// bvec[z][j] = xb[z][j,:] . wtld — wave-per-row, 64 rows/block.
__global__ void bvec_k(const __bf16* __restrict__ xb, const float* __restrict__ wtld,
                       float* __restrict__ bvec) {
  xb += (size_t)blockIdx.y * XB_STRIDE;
  bvec += (size_t)blockIdx.y * 4096;
  int tid = threadIdx.x, lane = tid & 63, w = tid >> 6;
  const float4* wt4 = (const float4*)wtld;
  float4 w0 = wt4[lane * 4], w1 = wt4[lane * 4 + 1];
  float4 w2 = wt4[lane * 4 + 2], w3 = wt4[lane * 4 + 3];
  int base = blockIdx.x * 64 + w;
#pragma unroll
  for (int i = 0; i < 16; i++) {
    int j = base + i * 4;
    const bf16x8* row = (const bf16x8*)(xb + (size_t)j * 1024);
    bf16x8 v0 = row[lane * 2], v1 = row[lane * 2 + 1];
    float s = (float)v0[0] * w0.x + (float)v0[1] * w0.y + (float)v0[2] * w0.z + (float)v0[3] * w0.w
            + (float)v0[4] * w1.x + (float)v0[5] * w1.y + (float)v0[6] * w1.z + (float)v0[7] * w1.w
            + (float)v1[0] * w2.x + (float)v1[1] * w2.y + (float)v1[2] * w2.z + (float)v1[3] * w2.w
            + (float)v1[4] * w3.x + (float)v1[5] * w3.y + (float)v1[6] * w3.z + (float)v1[7] * w3.w;
#pragma unroll
    for (int o = 32; o; o >>= 1) s += __shfl_xor(s, o, 64);
    if (lane == 0) bvec[j] = s;
  }
}

// ---------------------------------------------------------------------------
// 128x128 depth-2 pipelined core (round-6): used by PV and the Mt precompute.
__device__ __forceinline__ void gemm128_core(const __bf16* __restrict__ A, int lda, int m0,
                                             const __bf16* __restrict__ B, int ldb, int n0,
                                             int nt, __bf16 (*As)[4096], __bf16 (*Bs)[4096],
                                             f32x4 acc[4][4]) {
  const int tid = threadIdx.x;
  const int lane = tid & 63;
  const int wid = tid >> 6;
  const int wr = wid >> 1, wc = wid & 1;
  const int lr = lane & 15;
  const int lk = (lane >> 4) << 3;
  const int srow = tid >> 2;
  const int skq = (tid & 3) << 3;
  const __bf16* ga = A + (long)(m0 + srow) * lda + skq;
  const __bf16* gb = B + (long)(n0 + srow) * ldb + skq;

#define STAGE(t, j) do {                                                                                             \
    int k0_ = (t) * 32;                                                                                              \
    __builtin_amdgcn_global_load_lds((const AS1 void*)(ga + k0_),            (AS3 void*)(As[j] + tid * 8),        16, 0, 0); \
    __builtin_amdgcn_global_load_lds((const AS1 void*)(ga + k0_ + 64 * lda), (AS3 void*)(As[j] + tid * 8 + 2048), 16, 0, 0); \
    __builtin_amdgcn_global_load_lds((const AS1 void*)(gb + k0_),            (AS3 void*)(Bs[j] + tid * 8),        16, 0, 0); \
    __builtin_amdgcn_global_load_lds((const AS1 void*)(gb + k0_ + 64 * ldb), (AS3 void*)(Bs[j] + tid * 8 + 2048), 16, 0, 0); \
  } while (0)

  STAGE(0, 0);
  if (nt > 1) STAGE(1, 1);

  for (int t = 0; t < nt; ++t) {
    const int j = t & 1;
    if (t + 1 < nt) asm volatile("s_waitcnt vmcnt(4)" ::: "memory");
    else            asm volatile("s_waitcnt vmcnt(0)" ::: "memory");
    __builtin_amdgcn_s_barrier();
    __builtin_amdgcn_sched_barrier(0);

    bf16x8 af[4], bfr[4];
#pragma unroll
    for (int m = 0; m < 4; m++)
      af[m] = *(const bf16x8*)(As[j] + (wr * 64 + m * 16 + lr) * 32 + lk);
#pragma unroll
    for (int n = 0; n < 4; n++)
      bfr[n] = *(const bf16x8*)(Bs[j] + (wc * 64 + n * 16 + lr) * 32 + lk);
#pragma unroll
    for (int m = 0; m < 4; m++)
#pragma unroll
      for (int n = 0; n < 4; n++)
        acc[m][n] = __builtin_amdgcn_mfma_f32_16x16x32_bf16(af[m], bfr[n], acc[m][n], 0, 0, 0);

    asm volatile("s_waitcnt lgkmcnt(0)" ::: "memory");
    __builtin_amdgcn_sched_barrier(0);
    __builtin_amdgcn_s_barrier();
    __builtin_amdgcn_sched_barrier(0);
    if (t + 2 < nt) STAGE(t + 2, j);
  }
#undef STAGE
}

// Mt = Wk Wq_s^T into Wcat rows [0,1024)
__global__ void wqwk_k(const __bf16* __restrict__ Wk_nb, const __bf16* __restrict__ Wq_nb,
                       __bf16* __restrict__ Wcat) {
  __shared__ __bf16 As[2][4096], Bs[2][4096];
  f32x4 acc[4][4] = {};
  int m0 = blockIdx.y * 128, n0 = blockIdx.x * 128;
  gemm128_core(Wk_nb, 1024, m0, Wq_nb, 1024, n0, 32, As, Bs, acc);

  const int lane = threadIdx.x & 63;
  const int wid = threadIdx.x >> 6;
  const int wr = wid >> 1, wc = wid & 1;
  const int lr = lane & 15;
  const int lg = (lane >> 4) * 4;
#pragma unroll
  for (int m = 0; m < 4; m++) {
    int rs = m0 + wr * 64 + m * 16 + lg;
#pragma unroll
    for (int n = 0; n < 4; n++) {
      int col = n0 + wc * 64 + n * 16 + lr;
#pragma unroll
      for (int r = 0; r < 4; r++)
        Wcat[(size_t)(rs + r) * 1024 + col] = (__bf16)acc[m][n][r];
    }
  }
}

// ---------------------------------------------------------------------------
// 256x128 (BM x BN), BK=32 streaming GEMM core — sized for 2 blocks/CU:
// 512 thr = 8 waves (2 wm x 4 wn); per-wave output 128x32 -> acc[8][2] (64 VGPR).
// LDS/buf: A[256][32] 16KB + B[128][32] 8KB = 24KB; 2 bufs = 48KB -> 2 blocks/CU
// at <=128 VGPR (__launch_bounds__(512,4)). Co-resident blocks hide the
// 2-barrier drain that capped the 1-block/CU 256^2 core (9250 cyc/K-tile vs
// ~620 MFMA pipe — sync-bound, round-12 audit).
// Swizzle (64B rows, derived + bank-checked: 16 lanes -> 8 groups x 2 = free):
//   store: wave-linear dest (w*1024B + l*16B per region); global source col
//          pre-swizzled  scol = ((slot ^ ((srow>>1)&3)) << 3) elems.
//   read:  byte col = (kg ^ ((lr>>1)&3)) << 4  (constant per lane).
// Staging: 3 gload_lds(16B)/thread/K-tile {A rows r, r+128; B row r}, r=tid>>2.
// Counted vmcnt(3): tile t+1 stays in flight across the tile-end barrier.
// ---------------------------------------------------------------------------
__device__ __forceinline__ void gemm256x128_core(const __bf16* __restrict__ A, int lda, int m0,
                                                 const __bf16* __restrict__ B, int ldb, int n0,
                                                 int nt, __bf16* lds, f32x4 (&acc)[8][2]) {
  const int tid = threadIdx.x;
  const int l = tid & 63;
  const int w = tid >> 6;
  const int wm = w >> 2, wn = w & 3;
  const int lr = l & 15, kg = l >> 4;
  // staging
  const int srow = tid >> 2;                       // 0..127
  const int scol = (((tid & 3) ^ ((srow >> 1) & 3)) << 3);
  const __bf16* gaA = A + (size_t)(m0 + srow) * lda + scol;
  const __bf16* gaA2 = gaA + (size_t)128 * lda;
  const __bf16* gbB = B + (size_t)(n0 + srow) * ldb + scol;
  const int dst = w * 512 + l * 8;                 // elems within region
  // reads
  const int rcol = (kg ^ ((lr >> 1) & 3)) << 4;    // bytes, per-lane constant
  const char* ldsc = (const char*)lds;
  const int arow = (wm * 128 + lr) * 64;           // byte base (mq adds mq*1024)
  const int brow = 16384 + (wn * 32 + lr) * 64;    // nq adds nq*1024

#define STG(T, J) do {                                                                                   \
    int ko_ = (T) * 32;                                                                                  \
    __builtin_amdgcn_global_load_lds((const AS1 void*)(gaA + ko_),  (AS3 void*)(lds + (J) * 12288 + dst),        16, 0, 0); \
    __builtin_amdgcn_global_load_lds((const AS1 void*)(gaA2 + ko_), (AS3 void*)(lds + (J) * 12288 + 4096 + dst), 16, 0, 0); \
    __builtin_amdgcn_global_load_lds((const AS1 void*)(gbB + ko_),  (AS3 void*)(lds + (J) * 12288 + 8192 + dst), 16, 0, 0); \
  } while (0)

  STG(0, 0);
  if (nt > 1) STG(1, 1);
  asm volatile("s_waitcnt vmcnt(3)" ::: "memory");
  __builtin_amdgcn_sched_barrier(0);
  __builtin_amdgcn_s_barrier();

  for (int t = 0; t < nt; ++t) {
    const int j = t & 1;
    const int jb = j * 24576;
    bf16x8 aR[8], bR[2];
#pragma unroll
    for (int mq = 0; mq < 8; mq++)
      aR[mq] = *(const bf16x8*)(ldsc + jb + arow + mq * 1024 + rcol);
#pragma unroll
    for (int nq = 0; nq < 2; nq++)
      bR[nq] = *(const bf16x8*)(ldsc + jb + brow + nq * 1024 + rcol);

    __builtin_amdgcn_s_setprio(1);
#pragma unroll
    for (int mq = 0; mq < 8; mq++)
#pragma unroll
      for (int nq = 0; nq < 2; nq++)
        acc[mq][nq] = __builtin_amdgcn_mfma_f32_16x16x32_bf16(aR[mq], bR[nq], acc[mq][nq], 0, 0, 0);
    __builtin_amdgcn_s_setprio(0);

    // all waves' reads of buf j done -> safe to restage it for tile t+2
    asm volatile("s_waitcnt lgkmcnt(0)" ::: "memory");
    __builtin_amdgcn_sched_barrier(0);
    __builtin_amdgcn_s_barrier();
    if (t + 2 < nt) {
      STG(t + 2, j);
      asm volatile("s_waitcnt vmcnt(3)" ::: "memory");   // t+1 landed, t+2 in flight
    } else if (t + 1 < nt) {
      asm volatile("s_waitcnt vmcnt(0)" ::: "memory");   // drain last tile
    }
    __builtin_amdgcn_sched_barrier(0);
    __builtin_amdgcn_s_barrier();
  }
#undef STG
}

// ---------------------------------------------------------------------------
// Q''/V projection (batched z): [4096 x 2048] = xb @ Wcat^T. Grid (16,16,NB)
// = 1024 blocks at 2/CU = exactly 2 residency rounds.
__global__ void __launch_bounds__(512, 4)
qkv_gemm_k(const __bf16* __restrict__ xb, const __bf16* __restrict__ Wcat,
           const float* __restrict__ bv, __bf16* __restrict__ Qb,
           __bf16* __restrict__ Vt) {
  size_t zo = (size_t)blockIdx.z * XB_STRIDE;
  xb += zo; Qb += zo; Vt += zo;
  __shared__ __bf16 lds[24576];   // 48 KB
  f32x4 acc[8][2] = {};
  int m0 = blockIdx.y * 256, n0 = blockIdx.x * 128;
  gemm256x128_core(xb, 1024, m0, Wcat, 1024, n0, 32, lds, acc);

  const int l = threadIdx.x & 63;
  const int w = threadIdx.x >> 6;
  const int wm = w >> 2, wn = w & 3;
  const int lr = l & 15;
  const int lg = (l >> 4) * 4;
#pragma unroll
  for (int mq = 0; mq < 8; mq++) {
    int rs = m0 + wm * 128 + mq * 16 + lg;
#pragma unroll
    for (int nq = 0; nq < 2; nq++) {
      int col = n0 + wn * 32 + nq * 16 + lr;
      if (col < 1024) {
#pragma unroll
        for (int r = 0; r < 4; r++)
          Qb[(rs + r) * 1024 + col] = (__bf16)acc[mq][nq][r];
      } else {
        float bias = bv[col - 1024];
        bf16x4 t4;
#pragma unroll
        for (int r = 0; r < 4; r++) t4[r] = (__bf16)(acc[mq][nq][r] + bias);
        *(bf16x4*)(Vt + (size_t)(col - 1024) * 4096 + rs) = t4;
      }
    }
  }
}

// ---------------------------------------------------------------------------
// QK^T (batched z): scores = Q'' @ xb^T. Grid (32,16,NB); tile active iff
// n0 <= m0+255  <=>  bx <= 2*by+1 (1088 active blocks, 2/CU).
__global__ void __launch_bounds__(512, 4)
qk_gemm_k(const __bf16* __restrict__ Qb, const __bf16* __restrict__ xb,
          float* __restrict__ sc) {
  if ((int)blockIdx.x > 2 * (int)blockIdx.y + 1) return;
  size_t zo = (size_t)blockIdx.z * XB_STRIDE;
  Qb += zo; xb += zo;
  sc += (size_t)blockIdx.z * SC_STRIDE;
  __shared__ __bf16 lds[24576];   // 48 KB
  f32x4 acc[8][2] = {};
  int m0 = blockIdx.y * 256, n0 = blockIdx.x * 128;
  gemm256x128_core(Qb, 1024, m0, xb, 1024, n0, 32, lds, acc);

  const int l = threadIdx.x & 63;
  const int w = threadIdx.x >> 6;
  const int wm = w >> 2, wn = w & 3;
  const int lr = l & 15;
  const int lg = (l >> 4) * 4;
#pragma unroll
  for (int mq = 0; mq < 8; mq++) {
    int rs = m0 + wm * 128 + mq * 16 + lg;
#pragma unroll
    for (int nq = 0; nq < 2; nq++) {
      int col = n0 + wn * 32 + nq * 16 + lr;
#pragma unroll
      for (int r = 0; r < 4; r++)
        sc[(size_t)(rs + r) * 4096 + col] = acc[mq][nq][r];
    }
  }
}

// ---------------------------------------------------------------------------
// Row softmax, causal + alibi + column bias b_j (batched: blockIdx.y).
__global__ void softmax_k(float* __restrict__ sc, const float* __restrict__ frame,
                          const float* __restrict__ alibi_p,
                          const float* __restrict__ bvec) {
  sc += (size_t)blockIdx.y * SC_STRIDE;
  bvec += (size_t)blockIdx.y * 4096;
  __shared__ float red[4];
  int s = blockIdx.x;
  float* srow = sc + (long)s * 4096;
  __bf16* prow = (__bf16*)(srow + 2048);
  int tid = threadIdx.x, lane = tid & 63, wid = tid >> 6;
  float sig = 1.0f / (1.0f + __expf(-alibi_p[0]));
  float fs = frame[s];
  int n = s + 1;
  int bound = ((s >> 7) + 1) << 7;
  int nv = (n + 3) >> 2;
  int bv = bound >> 2;

  const float4* srow4 = (const float4*)srow;
  const float4* fr4 = (const float4*)frame;
  const float4* bv4 = (const float4*)bvec;
  float4 vals[4];

  float mx = -3.4e38f;
#pragma unroll
  for (int it = 0; it < 4; it++) {
    int i = tid + it * 256;
    if (i < nv) {
      float4 v = srow4[i];
      float4 f = fr4[i];
      float4 bb = bv4[i];
      int t0 = i << 2;
      float a0 = (t0     < n) ? v.x + bb.x - sig * fabsf(f.x - fs) : -3.4e38f;
      float a1 = (t0 + 1 < n) ? v.y + bb.y - sig * fabsf(f.y - fs) : -3.4e38f;
      float a2 = (t0 + 2 < n) ? v.z + bb.z - sig * fabsf(f.z - fs) : -3.4e38f;
      float a3 = (t0 + 3 < n) ? v.w + bb.w - sig * fabsf(f.w - fs) : -3.4e38f;
      vals[it] = make_float4(a0, a1, a2, a3);
      mx = fmaxf(fmaxf(fmaxf(mx, a0), fmaxf(a1, a2)), a3);
    }
  }
#pragma unroll
  for (int o = 32; o; o >>= 1) mx = fmaxf(mx, __shfl_xor(mx, o, 64));
  if (lane == 0) red[wid] = mx;
  __syncthreads();
  mx = fmaxf(fmaxf(red[0], red[1]), fmaxf(red[2], red[3]));

  float sum = 0.0f;
#pragma unroll
  for (int it = 0; it < 4; it++) {
    int i = tid + it * 256;
    if (i < nv) {
      float4 v = vals[it];
      float e0 = __expf(v.x - mx), e1 = __expf(v.y - mx);
      float e2 = __expf(v.z - mx), e3 = __expf(v.w - mx);
      vals[it] = make_float4(e0, e1, e2, e3);
      sum += (e0 + e1) + (e2 + e3);
    }
  }
#pragma unroll
  for (int o = 32; o; o >>= 1) sum += __shfl_xor(sum, o, 64);
  __syncthreads();
  if (lane == 0) red[wid] = sum;
  __syncthreads();
  sum = red[0] + red[1] + red[2] + red[3];
  float inv = 1.0f / sum;

#pragma unroll
  for (int it = 0; it < 4; it++) {
    int i = tid + it * 256;
    if (i < bv) {
      bf16x4 o;
      if (i < nv) {
        float4 v = vals[it];
        o[0] = (__bf16)(v.x * inv); o[1] = (__bf16)(v.y * inv);
        o[2] = (__bf16)(v.z * inv); o[3] = (__bf16)(v.w * inv);
      } else {
        o[0] = o[1] = o[2] = o[3] = (__bf16)0.0f;
      }
      *(bf16x4*)(prow + (i << 2)) = o;
    }
  }
}

// ---------------------------------------------------------------------------
// PV (batched z): out[v][s] = sum_{t<=s} P[s,t] * Vt[v,t]; 128^2 core.
// Grid (32, 8, z): XCD grouping + depth reflection (round-9 win).
__global__ void pv_gemm_k(const __bf16* __restrict__ P, const __bf16* __restrict__ Vt,
                          float* __restrict__ outb) {
  int z = blockIdx.z;
  int mi = (z & 1) ? blockIdx.x : 31 - blockIdx.x;
  int n0 = blockIdx.y * 128;
  P    += (size_t)z * P_STRIDE;
  Vt   += (size_t)z * XB_STRIDE;
  outb += (size_t)z * OUT_STRIDE;
  __shared__ __bf16 As[2][4096], Bs[2][4096];
  f32x4 acc[4][4] = {};
  int m0 = mi * 128;
  gemm128_core(P, 8192, m0, Vt, 4096, n0, (m0 + 128) / 32, As, Bs, acc);

  const int lane = threadIdx.x & 63;
  const int wid = threadIdx.x >> 6;
  const int wr = wid >> 1, wc = wid & 1;
  const int lr = lane & 15;
  const int lg = (lane >> 4) * 4;
#pragma unroll
  for (int m = 0; m < 4; m++) {
    int rs = m0 + wr * 64 + m * 16 + lg;
#pragma unroll
    for (int n = 0; n < 4; n++) {
      int col = n0 + wc * 64 + n * 16 + lr;
      *(f32x4*)(outb + (long)col * 4096 + rs) = acc[m][n];
    }
  }
}

// ---------------------------------------------------------------------------

static inline char* align256(char* p) {
  return (char*)(((uintptr_t)p + 255) & ~(uintptr_t)255);
}

extern "C" void kernel_launch(void* const* d_in, const int* in_sizes, int n_in,
                              void* d_out, int out_size, void* d_ws, size_t ws_size,
                              hipStream_t stream) {
  const float* input = (const float*)d_in[0];   // [4][1024][4096]
  const float* frame = (const float*)d_in[1];   // [4096]
  const float* Wq = (const float*)d_in[2];
  const float* bq = (const float*)d_in[3];
  const float* Wk = (const float*)d_in[4];
  const float* bk = (const float*)d_in[5];      // unused: k-bias terms cancel in softmax
  const float* Wv = (const float*)d_in[6];
  const float* bv = (const float*)d_in[7];
  const float* alibi = (const float*)d_in[8];
  float* out = (float*)d_out;                   // [4][2048][4096]
  (void)bk;

  const size_t NEED_BATCHED = (size_t)12 * 1024 * 1024 + (1 << 20) +
                              3 * (4 * XB_STRIDE * 2) + 4 * SC_STRIDE * 4 + 4096;
  int NB = (ws_size >= NEED_BATCHED) ? 4 : 1;

  char* p = (char*)d_ws;
  __bf16* Wq_nb = (__bf16*)p;  p += (size_t)1024 * 1024 * 2;
  __bf16* Wk_nb = (__bf16*)p;  p += (size_t)1024 * 1024 * 2;
  __bf16* Wcat  = (__bf16*)p;  p += (size_t)2048 * 1024 * 2;   // rows 0-1023: Mt, 1024+: Wv^T
  float* wtld   = (float*)p;   p += 1024 * 4;
  float* bvec   = (float*)p;   p += NB * 4096 * 4;             p = align256(p);
  __bf16* xb = (__bf16*)p;  p += NB * XB_STRIDE * 2;           p = align256(p);
  __bf16* Qb = (__bf16*)p;  p += NB * XB_STRIDE * 2;           p = align256(p);
  __bf16* Vt = (__bf16*)p;  p += NB * XB_STRIDE * 2;           p = align256(p);
  float* sc = (float*)p;    // NB x [4096][4096] fp32; P aliased into row halves

  convert_w_k<<<dim3(1024, 2), 256, 0, stream>>>(Wq, Wk, Wq_nb, Wk_nb);
  transpose_wv_k<<<dim3(32, 32), dim3(32, 8), 0, stream>>>(Wv, Wcat);
  wqwk_k<<<dim3(8, 8), 256, 0, stream>>>(Wk_nb, Wq_nb, Wcat);
  wtld_k<<<1024, 256, 0, stream>>>(Wk, bq, wtld);

  for (int b0 = 0; b0 < 4; b0 += NB) {
    const float* inb = input + (size_t)b0 * XB_STRIDE;
    float* outtop = out + (size_t)b0 * OUT_STRIDE;
    float* outb = outtop + (size_t)1024 * 4096;
    transpose_x_k<<<dim3(128, 32, NB), dim3(32, 8), 0, stream>>>(inb, xb, outtop);
    bvec_k<<<dim3(64, NB), 256, 0, stream>>>(xb, wtld, bvec);
    qkv_gemm_k<<<dim3(16, 16, NB), 512, 0, stream>>>(xb, Wcat, bv, Qb, Vt);
    qk_gemm_k<<<dim3(32, 16, NB), 512, 0, stream>>>(Qb, xb, sc);
    softmax_k<<<dim3(4096, NB), 256, 0, stream>>>(sc, frame, alibi, bvec);
    pv_gemm_k<<<dim3(32, 8, NB), 256, 0, stream>>>((const __bf16*)((char*)sc + 8192), Vt, outb);
  }
}

// Round 15
// 439.545 us; speedup vs baseline: 1.0474x; 1.0286x over previous
//
#include <hip/hip_runtime.h>
#include <cstdint>

#define AS1 __attribute__((address_space(1)))
#define AS3 __attribute__((address_space(3)))

typedef __bf16 bf16x8 __attribute__((ext_vector_type(8)));
typedef __bf16 bf16x4 __attribute__((ext_vector_type(4)));
typedef float  f32x4  __attribute__((ext_vector_type(4)));

// Per-batch element strides
#define XB_STRIDE   4194304ul   // 4096*1024 bf16 (also Qb, Kb, Vt, input-slice fp32)
#define SC_STRIDE   16777216ul  // 4096*4096 fp32
#define P_STRIDE    33554432ul  // score batch stride in bf16 units
#define OUT_STRIDE  8388608ul   // 2048*4096 fp32

// ---------------------------------------------------------------------------
// input slice [1024][4096] fp32 -> xb [4096][1024] bf16 (tiled transpose),
// FUSED with the fp32 identity copy into the output top-half (r12-verified).
__global__ void transpose_x_k(const float* __restrict__ in, __bf16* __restrict__ out,
                              float* __restrict__ outtop) {
  in     += (size_t)blockIdx.z * XB_STRIDE;
  out    += (size_t)blockIdx.z * XB_STRIDE;
  outtop += (size_t)blockIdx.z * OUT_STRIDE;
  __shared__ float t[32][33];
  int s0 = blockIdx.x * 32, c0 = blockIdx.y * 32;
  int tx = threadIdx.x, ty = threadIdx.y;
#pragma unroll
  for (int i = 0; i < 4; i++) {
    int idx = (c0 + ty + i * 8) * 4096 + s0 + tx;
    float v = in[idx];
    t[ty + i * 8][tx] = v;
    outtop[idx] = v;                   // fp32 passthrough to out[b][c][s], c<1024
  }
  __syncthreads();
#pragma unroll
  for (int i = 0; i < 4; i++)
    out[(s0 + ty + i * 8) * 1024 + c0 + tx] = (__bf16)t[tx][ty + i * 8];
}

// Wq/Wk/Wv [1024][1024] fp32 -> Wt [3072][1024] bf16 transposed, Q slice pre-scaled 1/32
__global__ void transpose_w_k(const float* __restrict__ Wq, const float* __restrict__ Wk,
                              const float* __restrict__ Wv, __bf16* __restrict__ Wt) {
  __shared__ float t[32][33];
  int sel = blockIdx.z;
  const float* W = sel == 0 ? Wq : (sel == 1 ? Wk : Wv);
  float scale = sel == 0 ? 0.03125f : 1.0f;
  int n0 = blockIdx.x * 32, c0 = blockIdx.y * 32;
  int tx = threadIdx.x, ty = threadIdx.y;
#pragma unroll
  for (int i = 0; i < 4; i++)
    t[ty + i * 8][tx] = W[(c0 + ty + i * 8) * 1024 + n0 + tx];
  __syncthreads();
#pragma unroll
  for (int i = 0; i < 4; i++)
    Wt[(sel * 1024 + n0 + ty + i * 8) * 1024 + c0 + tx] = (__bf16)(t[tx][ty + i * 8] * scale);
}

__global__ void bcat_k(const float* __restrict__ bq, const float* __restrict__ bk,
                       const float* __restrict__ bv, float* __restrict__ bcat) {
  int n = blockIdx.x * 256 + threadIdx.x;       // 3072 total
  float v = n < 1024 ? bq[n] * 0.03125f : (n < 2048 ? bk[n - 1024] : bv[n - 2048]);
  bcat[n] = v;
}

// ---------------------------------------------------------------------------
// 256x256 BK=64 streaming GEMM core (round 10; bank-conflict-free swizzle,
// counted vmcnt, 2 barriers/K-tile).
// ---------------------------------------------------------------------------
template<int MH, int NH>
__device__ __forceinline__ void mf_quad(f32x4 (&acc)[8][4], bf16x8 (&aR)[4][2],
                                        bf16x8 (&br)[2][2]) {
#pragma unroll
  for (int q = 0; q < 4; q++)
#pragma unroll
    for (int r = 0; r < 2; r++) {
      acc[MH * 4 + q][NH * 2 + r] = __builtin_amdgcn_mfma_f32_16x16x32_bf16(
          aR[q][0], br[r][0], acc[MH * 4 + q][NH * 2 + r], 0, 0, 0);
      acc[MH * 4 + q][NH * 2 + r] = __builtin_amdgcn_mfma_f32_16x16x32_bf16(
          aR[q][1], br[r][1], acc[MH * 4 + q][NH * 2 + r], 0, 0, 0);
    }
}

__device__ __forceinline__ void gemm256_core(const __bf16* __restrict__ A, int lda, int m0,
                                             const __bf16* __restrict__ B, int ldb, int n0,
                                             __bf16* lds, f32x4 (&acc)[8][4]) {
  const int tid = threadIdx.x;
  const int l = tid & 63;
  const int w = tid >> 6;
  const int wm = w >> 2, wn = w & 3;
  const int lr = l & 15, kg = l >> 4;
  const int lrow = l >> 3;
  const int scol = ((l & 7) ^ lrow) << 3;
  const int xorv = (lr & 7) << 4;
  const int cc0 = (kg << 4) ^ xorv;
  const int cc1 = (64 | (kg << 4)) ^ xorv;
  const int ch = w * 2;
  const char* ldsA = (const char*)lds + wm * 16384;
  const char* ldsB = (const char*)lds + 32768 + (wn >> 1) * 16384;
  const int browb = (wn & 1) * 64;

#define STG8(PTR, LD, BASE0, H, TT, JB, OPOFF) do {                                              \
    const __bf16* sp_ = (PTR) + (size_t)((BASE0) + (H) * 128 + ch * 8 + lrow) * (LD) +           \
                        (TT) * 64 + scol;                                                        \
    __bf16* dp_ = lds + ((JB) * 32768 + (OPOFF) + (H) * 8192 + ch * 512);                        \
    __builtin_amdgcn_global_load_lds((const AS1 void*)sp_,                   (AS3 void*)dp_,         16, 0, 0); \
    __builtin_amdgcn_global_load_lds((const AS1 void*)(sp_ + (size_t)8 * (LD)), (AS3 void*)(dp_ + 512), 16, 0, 0); \
  } while (0)
#define STGA(H, TT, JB) STG8(A, lda, m0, H, TT, JB, 0)
#define STGB(H, TT, JB) STG8(B, ldb, n0, H, TT, JB, 16384)
#define LDAF(dst, MH_, Q_) do {                                                                  \
    const char* p_ = ldsA + jbyte + ((MH_) * 64 + (Q_) * 16 + lr) * 128;                         \
    (dst)[0] = *(const bf16x8*)(p_ + cc0);                                                       \
    (dst)[1] = *(const bf16x8*)(p_ + cc1);                                                       \
  } while (0)
#define LDBF(dst, NH_, R_) do {                                                                  \
    const char* p_ = ldsB + jbyte + (browb + ((NH_) * 2 + (R_)) * 16 + lr) * 128;                \
    (dst)[0] = *(const bf16x8*)(p_ + cc0);                                                       \
    (dst)[1] = *(const bf16x8*)(p_ + cc1);                                                       \
  } while (0)

  STGA(0, 0, 0); STGA(1, 0, 0); STGB(0, 0, 0); STGB(1, 0, 0);
  STGB(0, 1, 1); STGA(0, 1, 1);
  asm volatile("s_waitcnt vmcnt(4)" ::: "memory");
  __builtin_amdgcn_sched_barrier(0);
  __builtin_amdgcn_s_barrier();

  bf16x8 aR[4][2], b0r[2][2], b1r[2][2];
  for (int t = 0; t < 16; ++t) {
    const int j = t & 1, jo = j ^ 1;
    const int jbyte = j * 65536;

#pragma unroll
    for (int q = 0; q < 4; q++) LDAF(aR[q], 0, q);
#pragma unroll
    for (int r = 0; r < 2; r++) LDBF(b0r[r], 0, r);
#pragma unroll
    for (int r = 0; r < 2; r++) LDBF(b1r[r], 1, r);
    if (t < 15) { STGA(1, t + 1, jo); STGB(1, t + 1, jo); }

    __builtin_amdgcn_s_setprio(1);
    mf_quad<0, 0>(acc, aR, b0r);
    mf_quad<0, 1>(acc, aR, b1r);
    __builtin_amdgcn_s_setprio(0);

#pragma unroll
    for (int q = 0; q < 4; q++) LDAF(aR[q], 1, q);
    __builtin_amdgcn_s_setprio(1);
    mf_quad<1, 1>(acc, aR, b1r);
    __builtin_amdgcn_s_setprio(0);

    asm volatile("s_waitcnt lgkmcnt(0)" ::: "memory");
    __builtin_amdgcn_sched_barrier(0);
    __builtin_amdgcn_s_barrier();
    if (t < 14) { STGB(0, t + 2, j); STGA(0, t + 2, j); }

    __builtin_amdgcn_s_setprio(1);
    mf_quad<1, 0>(acc, aR, b0r);
    __builtin_amdgcn_s_setprio(0);

    if (t < 14) asm volatile("s_waitcnt vmcnt(4)" ::: "memory");
    else        asm volatile("s_waitcnt vmcnt(0)" ::: "memory");
    __builtin_amdgcn_sched_barrier(0);
    __builtin_amdgcn_s_barrier();
  }
#undef STG8
#undef STGA
#undef STGB
#undef LDAF
#undef LDBF
}

// ---------------------------------------------------------------------------
// QKV fused projection (batched z), 256x256 streaming: [4096 x 3072] = xb @ Wt^T
__global__ void __launch_bounds__(512, 1)
qkv_gemm_k(const __bf16* __restrict__ xb, const __bf16* __restrict__ Wt,
           const float* __restrict__ bcat, __bf16* __restrict__ Qb,
           __bf16* __restrict__ Kb, __bf16* __restrict__ Vt) {
  size_t zo = (size_t)blockIdx.z * XB_STRIDE;
  xb += zo; Qb += zo; Kb += zo; Vt += zo;
  __shared__ __bf16 lds[65536];   // 128 KB
  f32x4 acc[8][4] = {};
  int m0 = blockIdx.y * 256, n0 = blockIdx.x * 256;
  gemm256_core(xb, 1024, m0, Wt, 1024, n0, lds, acc);

  const int l = threadIdx.x & 63;
  const int w = threadIdx.x >> 6;
  const int wm = w >> 2, wn = w & 3;
  const int lr = l & 15;
  const int lg = (l >> 4) * 4;
#pragma unroll
  for (int am = 0; am < 8; am++) {
    int rs = m0 + wm * 128 + am * 16 + lg;
#pragma unroll
    for (int an = 0; an < 4; an++) {
      int col = n0 + wn * 64 + an * 16 + lr;
      float bias = bcat[col];
      if (col < 1024) {
#pragma unroll
        for (int r = 0; r < 4; r++)
          Qb[(rs + r) * 1024 + col] = (__bf16)(acc[am][an][r] + bias);
      } else if (col < 2048) {
#pragma unroll
        for (int r = 0; r < 4; r++)
          Kb[(rs + r) * 1024 + (col - 1024)] = (__bf16)(acc[am][an][r] + bias);
      } else {
        bf16x4 t4;
#pragma unroll
        for (int r = 0; r < 4; r++) t4[r] = (__bf16)(acc[am][an][r] + bias);
        *(bf16x4*)(Vt + (size_t)(col - 2048) * 4096 + rs) = t4;
      }
    }
  }
}

// ---------------------------------------------------------------------------
// QK^T (batched z), 256x256 streaming. Upper-tri 256-tiles skipped.
__global__ void __launch_bounds__(512, 1)
qk_gemm_k(const __bf16* __restrict__ Qb, const __bf16* __restrict__ Kb,
          float* __restrict__ sc) {
  if (blockIdx.x > blockIdx.y) return;
  size_t zo = (size_t)blockIdx.z * XB_STRIDE;
  Qb += zo; Kb += zo;
  sc += (size_t)blockIdx.z * SC_STRIDE;
  __shared__ __bf16 lds[65536];   // 128 KB
  f32x4 acc[8][4] = {};
  int m0 = blockIdx.y * 256, n0 = blockIdx.x * 256;
  gemm256_core(Qb, 1024, m0, Kb, 1024, n0, lds, acc);

  const int l = threadIdx.x & 63;
  const int w = threadIdx.x >> 6;
  const int wm = w >> 2, wn = w & 3;
  const int lr = l & 15;
  const int lg = (l >> 4) * 4;
#pragma unroll
  for (int am = 0; am < 8; am++) {
    int rs = m0 + wm * 128 + am * 16 + lg;
#pragma unroll
    for (int an = 0; an < 4; an++) {
      int col = n0 + wn * 64 + an * 16 + lr;
#pragma unroll
      for (int r = 0; r < 4; r++)
        sc[(size_t)(rs + r) * 4096 + col] = acc[am][an][r];
    }
  }
}

// ---------------------------------------------------------------------------
// 128x128 depth-2 pipelined core (round-6), kept for PV.
__device__ __forceinline__ void gemm128_core(const __bf16* __restrict__ A, int lda, int m0,
                                             const __bf16* __restrict__ B, int ldb, int n0,
                                             int nt, __bf16 (*As)[4096], __bf16 (*Bs)[4096],
                                             f32x4 acc[4][4]) {
  const int tid = threadIdx.x;
  const int lane = tid & 63;
  const int wid = tid >> 6;
  const int wr = wid >> 1, wc = wid & 1;
  const int lr = lane & 15;
  const int lk = (lane >> 4) << 3;
  const int srow = tid >> 2;
  const int skq = (tid & 3) << 3;
  const __bf16* ga = A + (long)(m0 + srow) * lda + skq;
  const __bf16* gb = B + (long)(n0 + srow) * ldb + skq;

#define STAGE(t, j) do {                                                                                             \
    int k0_ = (t) * 32;                                                                                              \
    __builtin_amdgcn_global_load_lds((const AS1 void*)(ga + k0_),            (AS3 void*)(As[j] + tid * 8),        16, 0, 0); \
    __builtin_amdgcn_global_load_lds((const AS1 void*)(ga + k0_ + 64 * lda), (AS3 void*)(As[j] + tid * 8 + 2048), 16, 0, 0); \
    __builtin_amdgcn_global_load_lds((const AS1 void*)(gb + k0_),            (AS3 void*)(Bs[j] + tid * 8),        16, 0, 0); \
    __builtin_amdgcn_global_load_lds((const AS1 void*)(gb + k0_ + 64 * ldb), (AS3 void*)(Bs[j] + tid * 8 + 2048), 16, 0, 0); \
  } while (0)

  STAGE(0, 0);
  if (nt > 1) STAGE(1, 1);

  for (int t = 0; t < nt; ++t) {
    const int j = t & 1;
    if (t + 1 < nt) asm volatile("s_waitcnt vmcnt(4)" ::: "memory");
    else            asm volatile("s_waitcnt vmcnt(0)" ::: "memory");
    __builtin_amdgcn_s_barrier();
    __builtin_amdgcn_sched_barrier(0);

    bf16x8 af[4], bfr[4];
#pragma unroll
    for (int m = 0; m < 4; m++)
      af[m] = *(const bf16x8*)(As[j] + (wr * 64 + m * 16 + lr) * 32 + lk);
#pragma unroll
    for (int n = 0; n < 4; n++)
      bfr[n] = *(const bf16x8*)(Bs[j] + (wc * 64 + n * 16 + lr) * 32 + lk);
#pragma unroll
    for (int m = 0; m < 4; m++)
#pragma unroll
      for (int n = 0; n < 4; n++)
        acc[m][n] = __builtin_amdgcn_mfma_f32_16x16x32_bf16(af[m], bfr[n], acc[m][n], 0, 0, 0);

    asm volatile("s_waitcnt lgkmcnt(0)" ::: "memory");
    __builtin_amdgcn_sched_barrier(0);
    __builtin_amdgcn_s_barrier();
    __builtin_amdgcn_sched_barrier(0);
    if (t + 2 < nt) STAGE(t + 2, j);
  }
#undef STAGE
}

// ---------------------------------------------------------------------------
// Row softmax, causal + alibi (batched: blockIdx.y). Register-resident rows;
// P bf16 written in place into the second 8KB half of each 16KB score row.
__global__ void softmax_k(float* __restrict__ sc, const float* __restrict__ frame,
                          const float* __restrict__ alibi_p) {
  sc += (size_t)blockIdx.y * SC_STRIDE;
  __shared__ float red[4];
  int s = blockIdx.x;
  float* srow = sc + (long)s * 4096;
  __bf16* prow = (__bf16*)(srow + 2048);
  int tid = threadIdx.x, lane = tid & 63, wid = tid >> 6;
  float sig = 1.0f / (1.0f + __expf(-alibi_p[0]));
  float fs = frame[s];
  int n = s + 1;
  int bound = ((s >> 7) + 1) << 7;
  int nv = (n + 3) >> 2;
  int bv = bound >> 2;

  const float4* srow4 = (const float4*)srow;
  const float4* fr4 = (const float4*)frame;
  float4 vals[4];

  float mx = -3.4e38f;
#pragma unroll
  for (int it = 0; it < 4; it++) {
    int i = tid + it * 256;
    if (i < nv) {
      float4 v = srow4[i];
      float4 f = fr4[i];
      int t0 = i << 2;
      float a0 = (t0     < n) ? v.x - sig * fabsf(f.x - fs) : -3.4e38f;
      float a1 = (t0 + 1 < n) ? v.y - sig * fabsf(f.y - fs) : -3.4e38f;
      float a2 = (t0 + 2 < n) ? v.z - sig * fabsf(f.z - fs) : -3.4e38f;
      float a3 = (t0 + 3 < n) ? v.w - sig * fabsf(f.w - fs) : -3.4e38f;
      vals[it] = make_float4(a0, a1, a2, a3);
      mx = fmaxf(fmaxf(fmaxf(mx, a0), fmaxf(a1, a2)), a3);
    }
  }
#pragma unroll
  for (int o = 32; o; o >>= 1) mx = fmaxf(mx, __shfl_xor(mx, o, 64));
  if (lane == 0) red[wid] = mx;
  __syncthreads();
  mx = fmaxf(fmaxf(red[0], red[1]), fmaxf(red[2], red[3]));

  float sum = 0.0f;
#pragma unroll
  for (int it = 0; it < 4; it++) {
    int i = tid + it * 256;
    if (i < nv) {
      float4 v = vals[it];
      float e0 = __expf(v.x - mx), e1 = __expf(v.y - mx);
      float e2 = __expf(v.z - mx), e3 = __expf(v.w - mx);
      vals[it] = make_float4(e0, e1, e2, e3);
      sum += (e0 + e1) + (e2 + e3);
    }
  }
#pragma unroll
  for (int o = 32; o; o >>= 1) sum += __shfl_xor(sum, o, 64);
  __syncthreads();
  if (lane == 0) red[wid] = sum;
  __syncthreads();
  sum = red[0] + red[1] + red[2] + red[3];
  float inv = 1.0f / sum;

#pragma unroll
  for (int it = 0; it < 4; it++) {
    int i = tid + it * 256;
    if (i < bv) {
      bf16x4 o;
      if (i < nv) {
        float4 v = vals[it];
        o[0] = (__bf16)(v.x * inv); o[1] = (__bf16)(v.y * inv);
        o[2] = (__bf16)(v.z * inv); o[3] = (__bf16)(v.w * inv);
      } else {
        o[0] = o[1] = o[2] = o[3] = (__bf16)0.0f;
      }
      *(bf16x4*)(prow + (i << 2)) = o;
    }
  }
}

// ---------------------------------------------------------------------------
// PV (batched z): out[v][s] = sum_{t<=s} P[s,t] * Vt[v,t]; 128^2 core.
// Grid (32, 8, z): blockIdx.x = depth group, blockIdx.y = n-tile (v).
// XCD locality (round-9 win): id mod 8 = bx mod 8 -> the 8 n-tile blocks
// sharing a P[mi] panel land on the same XCD. Depth reflection keeps per-CU
// K-work constant. mi = (z&1) ? bx : 31-bx is bijective per z.
__global__ void pv_gemm_k(const __bf16* __restrict__ P, const __bf16* __restrict__ Vt,
                          float* __restrict__ outb) {
  int z = blockIdx.z;
  int mi = (z & 1) ? blockIdx.x : 31 - blockIdx.x;   // depth reflection
  int n0 = blockIdx.y * 128;
  P    += (size_t)z * P_STRIDE;
  Vt   += (size_t)z * XB_STRIDE;
  outb += (size_t)z * OUT_STRIDE;
  __shared__ __bf16 As[2][4096], Bs[2][4096];
  f32x4 acc[4][4] = {};
  int m0 = mi * 128;
  gemm128_core(P, 8192, m0, Vt, 4096, n0, (m0 + 128) / 32, As, Bs, acc);

  const int lane = threadIdx.x & 63;
  const int wid = threadIdx.x >> 6;
  const int wr = wid >> 1, wc = wid & 1;
  const int lr = lane & 15;
  const int lg = (lane >> 4) * 4;
#pragma unroll
  for (int m = 0; m < 4; m++) {
    int rs = m0 + wr * 64 + m * 16 + lg;
#pragma unroll
    for (int n = 0; n < 4; n++) {
      int col = n0 + wc * 64 + n * 16 + lr;   // v index
      *(f32x4*)(outb + (long)col * 4096 + rs) = acc[m][n];
    }
  }
}

// ---------------------------------------------------------------------------

static inline char* align256(char* p) {
  return (char*)(((uintptr_t)p + 255) & ~(uintptr_t)255);
}

extern "C" void kernel_launch(void* const* d_in, const int* in_sizes, int n_in,
                              void* d_out, int out_size, void* d_ws, size_t ws_size,
                              hipStream_t stream) {
  const float* input = (const float*)d_in[0];   // [4][1024][4096]
  const float* frame = (const float*)d_in[1];   // [4096]
  const float* Wq = (const float*)d_in[2];
  const float* bq = (const float*)d_in[3];
  const float* Wk = (const float*)d_in[4];
  const float* bk = (const float*)d_in[5];
  const float* Wv = (const float*)d_in[6];
  const float* bv = (const float*)d_in[7];
  const float* alibi = (const float*)d_in[8];
  float* out = (float*)d_out;                   // [4][2048][4096]

  const size_t NEED_BATCHED = (size_t)3072 * 1024 * 2 + 4096 +
                              4 * (4 * XB_STRIDE * 2) + 4 * SC_STRIDE * 4 + 2048;
  int NB = (ws_size >= NEED_BATCHED) ? 4 : 1;

  char* p = (char*)d_ws;
  __bf16* Wt = (__bf16*)p;  p += (size_t)3072 * 1024 * 2;
  float* bcat = (float*)p;  p += 3072 * 4;                    p = align256(p);
  __bf16* xb = (__bf16*)p;  p += NB * XB_STRIDE * 2;          p = align256(p);
  __bf16* Qb = (__bf16*)p;  p += NB * XB_STRIDE * 2;          p = align256(p);
  __bf16* Kb = (__bf16*)p;  p += NB * XB_STRIDE * 2;          p = align256(p);
  __bf16* Vt = (__bf16*)p;  p += NB * XB_STRIDE * 2;          p = align256(p);
  float* sc = (float*)p;    // NB x [4096][4096] fp32; P aliased into row halves

  transpose_w_k<<<dim3(32, 32, 3), dim3(32, 8), 0, stream>>>(Wq, Wk, Wv, Wt);
  bcat_k<<<12, 256, 0, stream>>>(bq, bk, bv, bcat);

  for (int b0 = 0; b0 < 4; b0 += NB) {
    const float* inb = input + (size_t)b0 * XB_STRIDE;
    float* outtop = out + (size_t)b0 * OUT_STRIDE;
    float* outb = outtop + (size_t)1024 * 4096;
    transpose_x_k<<<dim3(128, 32, NB), dim3(32, 8), 0, stream>>>(inb, xb, outtop);
    qkv_gemm_k<<<dim3(12, 16, NB), 512, 0, stream>>>(xb, Wt, bcat, Qb, Kb, Vt);
    qk_gemm_k<<<dim3(16, 16, NB), 512, 0, stream>>>(Qb, Kb, sc);
    softmax_k<<<dim3(4096, NB), 256, 0, stream>>>(sc, frame, alibi);
    pv_gemm_k<<<dim3(32, 8, NB), 256, 0, stream>>>((const __bf16*)((char*)sc + 8192), Vt, outb);
  }
}